// Round 1
// baseline (1221.677 us; speedup 1.0000x reference)
//
#include <hip/hip_runtime.h>
#include <math.h>

#define N_NODES 50000
#define N_EDGES 800000
#define ET (N_EDGES + N_NODES)   // 850000 with self loops
#define IN_CH 128
#define H 256
#define G_GRAPHS 128
#define NEG_SLOPE 0.2f

// ---------------------------------------------------------------- CSR build
__global__ __launch_bounds__(256) void init_counts(int* __restrict__ counts) {
    int i = blockIdx.x * 256 + threadIdx.x;
    if (i < N_NODES) counts[i] = 1;   // self loop
}

__global__ __launch_bounds__(256) void hist_kernel(const int* __restrict__ ei,
                                                   int* __restrict__ counts) {
    int e = blockIdx.x * 256 + threadIdx.x;
    if (e < N_EDGES) atomicAdd(&counts[ei[N_EDGES + e]], 1);
}

__global__ __launch_bounds__(256) void scan_block(const int* __restrict__ in,
                                                  int* __restrict__ incl,
                                                  int* __restrict__ blockSums) {
    __shared__ int s[256];
    int t = threadIdx.x;
    int i = blockIdx.x * 256 + t;
    int v = (i < N_NODES) ? in[i] : 0;
    s[t] = v;
    __syncthreads();
    for (int off = 1; off < 256; off <<= 1) {
        int x = 0;
        if (t >= off) x = s[t - off];
        __syncthreads();
        if (t >= off) s[t] += x;
        __syncthreads();
    }
    if (i < N_NODES) incl[i] = s[t];
    if (t == 255) blockSums[blockIdx.x] = s[255];
}

__global__ __launch_bounds__(256) void scan_sums(const int* __restrict__ blockSums,
                                                 int* __restrict__ blockOff, int nb) {
    __shared__ int s[256];
    int t = threadIdx.x;
    int v = (t < nb) ? blockSums[t] : 0;
    s[t] = v;
    __syncthreads();
    for (int off = 1; off < 256; off <<= 1) {
        int x = 0;
        if (t >= off) x = s[t - off];
        __syncthreads();
        if (t >= off) s[t] += x;
        __syncthreads();
    }
    if (t < nb) blockOff[t] = s[t] - v;   // exclusive
}

__global__ __launch_bounds__(256) void scan_finalize(const int* __restrict__ incl,
                                                     const int* __restrict__ blockOff,
                                                     int* __restrict__ indptr,
                                                     int* __restrict__ cursor) {
    int i = blockIdx.x * 256 + threadIdx.x;
    if (i < N_NODES) {
        int v = incl[i] + blockOff[i >> 8];
        indptr[i + 1] = v;
        if (i + 1 < N_NODES) cursor[i + 1] = v;
    }
    if (i == 0) { indptr[0] = 0; cursor[0] = 0; }
}

__global__ __launch_bounds__(256) void scatter_kernel(const int* __restrict__ ei,
                                                      int* __restrict__ cursor,
                                                      int* __restrict__ eids) {
    int e = blockIdx.x * 256 + threadIdx.x;
    if (e < ET) {
        int dst = (e < N_EDGES) ? ei[N_EDGES + e] : (e - N_EDGES);
        int pos = atomicAdd(&cursor[dst], 1);
        eids[pos] = e;
    }
}

// ---------------------------------------------------------------- fp32 GEMM
// C[M,Nc] = A[M,K] @ B[K,Nc], row-major. BM=BN=64, BK=16, 256 thr, 4x4/thread.
__global__ __launch_bounds__(256) void gemm_f32(const float* __restrict__ A,
                                                const float* __restrict__ B,
                                                float* __restrict__ C,
                                                int M, int Nc, int K) {
    __shared__ float As[16][64];
    __shared__ float Bs[16][64];
    int t = threadIdx.x;
    int m0 = blockIdx.x * 64, n0 = blockIdx.y * 64;
    int tm = (t >> 4) << 2, tn = (t & 15) << 2;
    float acc[4][4] = {};
    int a_row = t >> 2;           // 0..63
    int a_kq  = (t & 3) << 2;     // 0,4,8,12
    int b_col = t & 63;
    int b_r0  = t >> 6;           // 0..3

    for (int k0 = 0; k0 < K; k0 += 16) {
        int gr = m0 + a_row;
        float4 av = make_float4(0.f, 0.f, 0.f, 0.f);
        if (gr < M) av = *(const float4*)&A[(size_t)gr * K + k0 + a_kq];
        As[a_kq + 0][a_row] = av.x;
        As[a_kq + 1][a_row] = av.y;
        As[a_kq + 2][a_row] = av.z;
        As[a_kq + 3][a_row] = av.w;
#pragma unroll
        for (int p = 0; p < 4; p++) {
            int kr = b_r0 + (p << 2);
            Bs[kr][b_col] = B[(size_t)(k0 + kr) * Nc + n0 + b_col];
        }
        __syncthreads();
#pragma unroll
        for (int kk = 0; kk < 16; kk++) {
            float4 a = *(const float4*)&As[kk][tm];
            float4 b = *(const float4*)&Bs[kk][tn];
            acc[0][0] += a.x * b.x; acc[0][1] += a.x * b.y; acc[0][2] += a.x * b.z; acc[0][3] += a.x * b.w;
            acc[1][0] += a.y * b.x; acc[1][1] += a.y * b.y; acc[1][2] += a.y * b.z; acc[1][3] += a.y * b.w;
            acc[2][0] += a.z * b.x; acc[2][1] += a.z * b.y; acc[2][2] += a.z * b.z; acc[2][3] += a.z * b.w;
            acc[3][0] += a.w * b.x; acc[3][1] += a.w * b.y; acc[3][2] += a.w * b.z; acc[3][3] += a.w * b.w;
        }
        __syncthreads();
    }
#pragma unroll
    for (int i = 0; i < 4; i++) {
        int r = m0 + tm + i;
        if (r < M)
            *(float4*)&C[(size_t)r * Nc + n0 + tn] =
                make_float4(acc[i][0], acc[i][1], acc[i][2], acc[i][3]);
    }
}

// ------------------------------------------------- attention score pre-dots
__global__ __launch_bounds__(256) void sdot_kernel(const float* __restrict__ xp,
                                                   const float* __restrict__ a_src,
                                                   const float* __restrict__ a_dst,
                                                   float* __restrict__ s_src,
                                                   float* __restrict__ s_dst) {
    __shared__ float r1[256];
    __shared__ float r2[256];
    int n = blockIdx.x, t = threadIdx.x;
    float v = xp[(size_t)n * H + t];
    r1[t] = v * a_src[t];
    r2[t] = v * a_dst[t];
    __syncthreads();
    for (int off = 128; off > 0; off >>= 1) {
        if (t < off) { r1[t] += r1[t + off]; r2[t] += r2[t + off]; }
        __syncthreads();
    }
    if (t == 0) { s_src[n] = r1[0]; s_dst[n] = r2[0]; }
}

// --------------------------------------------------------- GAT aggregation
__global__ __launch_bounds__(256) void gat_agg(const float* __restrict__ xp,
                                               const float* __restrict__ s_src,
                                               const float* __restrict__ s_dst,
                                               const int* __restrict__ indptr,
                                               const int* __restrict__ eids,
                                               const int* __restrict__ src_arr,
                                               const float* __restrict__ bias,
                                               float* __restrict__ out) {
    __shared__ float red[256];
    __shared__ int   sL[128];
    __shared__ float wL[128];
    __shared__ float s_m, s_dinv;
    int n = blockIdx.x, t = threadIdx.x;
    int start = indptr[n];
    int deg = indptr[n + 1] - start;
    float sdn = s_dst[n];

    // pass 1: max
    float lm = -1e30f;
    for (int i = t; i < deg; i += 256) {
        int e = eids[start + i];
        int s = (e < N_EDGES) ? src_arr[e] : (e - N_EDGES);
        float v = s_src[s] + sdn;
        v = (v >= 0.f) ? v : NEG_SLOPE * v;
        lm = fmaxf(lm, v);
    }
    red[t] = lm;
    __syncthreads();
    for (int off = 128; off > 0; off >>= 1) {
        if (t < off) red[t] = fmaxf(red[t], red[t + off]);
        __syncthreads();
    }
    if (t == 0) s_m = red[0];
    __syncthreads();
    float m = s_m;
    __syncthreads();

    // pass 2: denom
    float ls = 0.f;
    for (int i = t; i < deg; i += 256) {
        int e = eids[start + i];
        int s = (e < N_EDGES) ? src_arr[e] : (e - N_EDGES);
        float v = s_src[s] + sdn;
        v = (v >= 0.f) ? v : NEG_SLOPE * v;
        ls += expf(v - m);
    }
    red[t] = ls;
    __syncthreads();
    for (int off = 128; off > 0; off >>= 1) {
        if (t < off) red[t] += red[t + off];
        __syncthreads();
    }
    if (t == 0) s_dinv = 1.f / red[0];
    __syncthreads();
    float dinv = s_dinv;

    // pass 3: weighted gather, chunks of 128 edges
    float acc = 0.f;
    for (int base = 0; base < deg; base += 128) {
        int cnt = min(128, deg - base);
        __syncthreads();
        if (t < cnt) {
            int e = eids[start + base + t];
            int s = (e < N_EDGES) ? src_arr[e] : (e - N_EDGES);
            float v = s_src[s] + sdn;
            v = (v >= 0.f) ? v : NEG_SLOPE * v;
            sL[t] = s;
            wL[t] = expf(v - m) * dinv;
        }
        __syncthreads();
        for (int j = 0; j < cnt; j++)
            acc += wL[j] * xp[(size_t)sL[j] * H + t];
    }
    float o = acc + bias[t];
    out[(size_t)n * H + t] = (o > 0.f) ? o : 0.f;   // relu wrapper
}

// ------------------------------------------------------------- GRU (fused)
__global__ __launch_bounds__(256) void transpose_wih(const float* __restrict__ W,
                                                     float* __restrict__ Wt) {
    int idx = blockIdx.x * 256 + threadIdx.x;   // 3H*H = 196608
    if (idx < 3 * H * H) {
        int j = idx / H, k = idx % H;
        Wt[k * (3 * H) + j] = W[idx];
    }
}

// h_out[n,t] = (1-z)*tanh(i_n + r*b_hh_n), 16 nodes/block, thread t owns cols t,t+256,t+512
__global__ __launch_bounds__(256) void gru_fused(const float* __restrict__ hin,
                                                 const float* __restrict__ Wt,
                                                 const float* __restrict__ b_ih,
                                                 const float* __restrict__ b_hh,
                                                 float* __restrict__ out) {
    __shared__ float As[16][16];
    __shared__ float Bs[16][768];
    int t = threadIdx.x;
    int m0 = blockIdx.x * 16;
    float ar[16], az[16], an[16];
#pragma unroll
    for (int i = 0; i < 16; i++) { ar[i] = 0.f; az[i] = 0.f; an[i] = 0.f; }
    int a_row = t >> 4, a_col = t & 15;

    for (int k0 = 0; k0 < H; k0 += 16) {
        As[a_col][a_row] = hin[(size_t)(m0 + a_row) * H + k0 + a_col];
#pragma unroll
        for (int i = 0; i < 48; i++) {
            int row = i / 3, col = (i % 3) * 256 + t;
            Bs[row][col] = Wt[(size_t)(k0 + row) * 768 + col];
        }
        __syncthreads();
#pragma unroll
        for (int kk = 0; kk < 16; kk++) {
            float br = Bs[kk][t], bz = Bs[kk][256 + t], bn = Bs[kk][512 + t];
#pragma unroll
            for (int iq = 0; iq < 4; iq++) {
                float4 a = *(const float4*)&As[kk][iq * 4];
                ar[iq*4+0] += a.x * br; az[iq*4+0] += a.x * bz; an[iq*4+0] += a.x * bn;
                ar[iq*4+1] += a.y * br; az[iq*4+1] += a.y * bz; an[iq*4+1] += a.y * bn;
                ar[iq*4+2] += a.z * br; az[iq*4+2] += a.z * bz; an[iq*4+2] += a.z * bn;
                ar[iq*4+3] += a.w * br; az[iq*4+3] += a.w * bz; an[iq*4+3] += a.w * bn;
            }
        }
        __syncthreads();
    }
    float bir = b_ih[t], biz = b_ih[256 + t], bin_ = b_ih[512 + t];
    float bhr = b_hh[t], bhz = b_hh[256 + t], bhn = b_hh[512 + t];
#pragma unroll
    for (int i = 0; i < 16; i++) {
        float r  = 1.f / (1.f + expf(-(ar[i] + bir + bhr)));
        float z  = 1.f / (1.f + expf(-(az[i] + biz + bhz)));
        float nn = tanhf(an[i] + bin_ + r * bhn);
        out[(size_t)(m0 + i) * H + t] = (1.f - z) * nn;
    }
}

// --------------------------------------------------------------- pooling
__global__ __launch_bounds__(256) void pool_kernel(const float* __restrict__ h,
                                                   const int* __restrict__ batch,
                                                   float* __restrict__ pooled) {
    int n = blockIdx.x, t = threadIdx.x;
    int g = batch[n];
    atomicAdd(&pooled[(size_t)g * H + t], h[(size_t)n * H + t]);
}

__global__ __launch_bounds__(256) void super_kernel(const float* __restrict__ pooled,
                                                    const float* __restrict__ Wf,
                                                    const float* __restrict__ bf,
                                                    float* __restrict__ sup) {
    __shared__ float smean[256];
    int t = threadIdx.x;
    float s = 0.f;
    for (int g = 0; g < G_GRAPHS; g++) s += pooled[(size_t)g * H + t];
    smean[t] = s / (float)G_GRAPHS;
    __syncthreads();
    float acc = 0.f;
    for (int k = 0; k < H; k++) acc += smean[k] * Wf[(size_t)t * H + k];
    acc += bf[t];
    sup[t] = fmaxf(acc, 0.f);
}

__global__ __launch_bounds__(256) void writeout(const float* __restrict__ pooled,
                                                const float* __restrict__ sup,
                                                float* __restrict__ out) {
    int idx = blockIdx.x * 256 + threadIdx.x;   // G*2H = 65536
    int g = idx >> 9, c = idx & 511;
    out[idx] = (c < H) ? pooled[(size_t)g * H + c] : sup[c - H];
}

// ---------------------------------------------------------------- launcher
extern "C" void kernel_launch(void* const* d_in, const int* in_sizes, int n_in,
                              void* d_out, int out_size, void* d_ws, size_t ws_size,
                              hipStream_t stream) {
    const float* x      = (const float*)d_in[0];
    const int*   ei     = (const int*)d_in[1];
    const int*   batch  = (const int*)d_in[2];
    const float* W0     = (const float*)d_in[3];
    const float* a_src0 = (const float*)d_in[4];
    const float* a_dst0 = (const float*)d_in[5];
    const float* b0     = (const float*)d_in[6];
    const float* W1     = (const float*)d_in[7];
    const float* a_src1 = (const float*)d_in[8];
    const float* a_dst1 = (const float*)d_in[9];
    const float* b1     = (const float*)d_in[10];
    const float* W_ih   = (const float*)d_in[11];
    // d_in[12] = W_hh unused (h0 = 0)
    const float* b_ih   = (const float*)d_in[13];
    const float* b_hh   = (const float*)d_in[14];
    const float* Wf     = (const float*)d_in[15];
    const float* bf     = (const float*)d_in[16];
    float* out = (float*)d_out;

    char* p = (char*)d_ws;
    auto alloc = [&](size_t bytes) -> void* {
        void* r = (void*)p;
        p += (bytes + 255) & ~(size_t)255;
        return r;
    };
    float* xpA    = (float*)alloc((size_t)N_NODES * H * 4);
    float* hB     = (float*)alloc((size_t)N_NODES * H * 4);
    float* s_src  = (float*)alloc((size_t)N_NODES * 4);
    float* s_dst  = (float*)alloc((size_t)N_NODES * 4);
    int*   counts = (int*)alloc((size_t)N_NODES * 4);
    int*   incl   = (int*)alloc((size_t)N_NODES * 4);
    int*   indptr = (int*)alloc((size_t)(N_NODES + 1) * 4);
    int*   cursor = (int*)alloc((size_t)N_NODES * 4);
    int*   eids   = (int*)alloc((size_t)ET * 4);
    int*   bSums  = (int*)alloc(256 * 4);
    int*   bOff   = (int*)alloc(256 * 4);
    float* Wt     = (float*)alloc((size_t)3 * H * H * 4);
    float* pooled = (float*)alloc((size_t)G_GRAPHS * H * 4);
    float* sup    = (float*)alloc((size_t)H * 4);

    const int SB = (N_NODES + 255) / 256;            // 196
    // CSR build
    init_counts<<<SB, 256, 0, stream>>>(counts);
    hist_kernel<<<(N_EDGES + 255) / 256, 256, 0, stream>>>(ei, counts);
    scan_block<<<SB, 256, 0, stream>>>(counts, incl, bSums);
    scan_sums<<<1, 256, 0, stream>>>(bSums, bOff, SB);
    scan_finalize<<<SB, 256, 0, stream>>>(incl, bOff, indptr, cursor);
    scatter_kernel<<<(ET + 255) / 256, 256, 0, stream>>>(ei, cursor, eids);

    dim3 gemm_grid((N_NODES + 63) / 64, H / 64);
    // GAT layer 0
    gemm_f32<<<gemm_grid, 256, 0, stream>>>(x, W0, xpA, N_NODES, H, IN_CH);
    sdot_kernel<<<N_NODES, 256, 0, stream>>>(xpA, a_src0, a_dst0, s_src, s_dst);
    gat_agg<<<N_NODES, 256, 0, stream>>>(xpA, s_src, s_dst, indptr, eids, ei, b0, hB);
    // GAT layer 1
    gemm_f32<<<gemm_grid, 256, 0, stream>>>(hB, W1, xpA, N_NODES, H, H);
    sdot_kernel<<<N_NODES, 256, 0, stream>>>(xpA, a_src1, a_dst1, s_src, s_dst);
    gat_agg<<<N_NODES, 256, 0, stream>>>(xpA, s_src, s_dst, indptr, eids, ei, b1, hB);
    // GRU
    transpose_wih<<<(3 * H * H + 255) / 256, 256, 0, stream>>>(W_ih, Wt);
    gru_fused<<<N_NODES / 16, 256, 0, stream>>>(hB, Wt, b_ih, b_hh, xpA);
    // pooling + super node
    hipMemsetAsync(pooled, 0, (size_t)G_GRAPHS * H * 4, stream);
    pool_kernel<<<N_NODES, 256, 0, stream>>>(xpA, batch, pooled);
    super_kernel<<<1, 256, 0, stream>>>(pooled, Wf, bf, sup);
    writeout<<<(G_GRAPHS * 2 * H) / 256, 256, 0, stream>>>(pooled, sup, out);
}

// Round 2
// 852.074 us; speedup vs baseline: 1.4338x; 1.4338x over previous
//
#include <hip/hip_runtime.h>
#include <math.h>

#define N_NODES 50000
#define N_EDGES 800000
#define ET (N_EDGES + N_NODES)   // 850000 with self loops
#define IN_CH 128
#define H 256
#define G_GRAPHS 128
#define NEG_SLOPE 0.2f
#define GRU_CHUNK 12544          // 98*128

typedef __attribute__((ext_vector_type(8))) short short8;
typedef __attribute__((ext_vector_type(4))) float f32x4;

__device__ inline unsigned short f2bf(float v) {
    unsigned u = __float_as_uint(v);
    unsigned r = (u + 0x7FFFu + ((u >> 16) & 1u)) >> 16;
    return (unsigned short)r;
}
__device__ inline float bf2f(unsigned short v) {
    return __uint_as_float(((unsigned)v) << 16);
}

// ---------------------------------------------------------------- CSR build
__global__ __launch_bounds__(256) void init_counts(int* __restrict__ counts) {
    int i = blockIdx.x * 256 + threadIdx.x;
    if (i < N_NODES) counts[i] = 1;   // self loop
}

__global__ __launch_bounds__(256) void hist_kernel(const int* __restrict__ ei,
                                                   int* __restrict__ counts) {
    int e = blockIdx.x * 256 + threadIdx.x;
    if (e < N_EDGES) atomicAdd(&counts[ei[N_EDGES + e]], 1);
}

__global__ __launch_bounds__(256) void scan_block(const int* __restrict__ in,
                                                  int* __restrict__ incl,
                                                  int* __restrict__ blockSums) {
    __shared__ int s[256];
    int t = threadIdx.x;
    int i = blockIdx.x * 256 + t;
    int v = (i < N_NODES) ? in[i] : 0;
    s[t] = v;
    __syncthreads();
    for (int off = 1; off < 256; off <<= 1) {
        int x = 0;
        if (t >= off) x = s[t - off];
        __syncthreads();
        if (t >= off) s[t] += x;
        __syncthreads();
    }
    if (i < N_NODES) incl[i] = s[t];
    if (t == 255) blockSums[blockIdx.x] = s[255];
}

__global__ __launch_bounds__(256) void scan_sums(const int* __restrict__ blockSums,
                                                 int* __restrict__ blockOff, int nb) {
    __shared__ int s[256];
    int t = threadIdx.x;
    int v = (t < nb) ? blockSums[t] : 0;
    s[t] = v;
    __syncthreads();
    for (int off = 1; off < 256; off <<= 1) {
        int x = 0;
        if (t >= off) x = s[t - off];
        __syncthreads();
        if (t >= off) s[t] += x;
        __syncthreads();
    }
    if (t < nb) blockOff[t] = s[t] - v;   // exclusive
}

__global__ __launch_bounds__(256) void scan_finalize(const int* __restrict__ incl,
                                                     const int* __restrict__ blockOff,
                                                     int* __restrict__ indptr,
                                                     int* __restrict__ cursor) {
    int i = blockIdx.x * 256 + threadIdx.x;
    if (i < N_NODES) {
        int v = incl[i] + blockOff[i >> 8];
        indptr[i + 1] = v;
        if (i + 1 < N_NODES) cursor[i + 1] = v;
    }
    if (i == 0) { indptr[0] = 0; cursor[0] = 0; }
}

__global__ __launch_bounds__(256) void scatter_kernel(const int* __restrict__ ei,
                                                      int* __restrict__ cursor,
                                                      int* __restrict__ eids) {
    int e = blockIdx.x * 256 + threadIdx.x;
    if (e < ET) {
        int dst = (e < N_EDGES) ? ei[N_EDGES + e] : (e - N_EDGES);
        int pos = atomicAdd(&cursor[dst], 1);
        eids[pos] = e;
    }
}

// ---------------------------------------------------------------- converts
__global__ __launch_bounds__(256) void convert_f2bf(const float* __restrict__ in,
                                                    unsigned short* __restrict__ out, int n) {
    int i = blockIdx.x * 256 + threadIdx.x;
    if (i < n) out[i] = f2bf(in[i]);
}

// W [K][Nc] fp32 row-major -> Wt [Nc][K] bf16
__global__ __launch_bounds__(256) void transpose_f2bf(const float* __restrict__ W,
                                                      unsigned short* __restrict__ Wt,
                                                      int K, int Nc) {
    int idx = blockIdx.x * 256 + threadIdx.x;
    if (idx < K * Nc) {
        int k = idx / Nc, n = idx % Nc;
        Wt[(size_t)n * K + k] = f2bf(W[idx]);
    }
}

// ------------------------------------------------------------ MFMA GEMM
// C[M,Ntot] (+= bias? no) = A[M,K](bf16) @ Bt[Ntot,K]^T (bf16), fp32 acc.
// 128x128 tile, BK=32, 256 thr = 4 waves (2x2 of 64x64), 4x4 16x16x32 tiles/wave.
__device__ inline void storeC(float* C, size_t idx, float v) { C[idx] = v; }
__device__ inline void storeC(unsigned short* C, size_t idx, float v) { C[idx] = f2bf(v); }

template <typename TC>
__global__ __launch_bounds__(256) void gemm_mfma(const unsigned short* __restrict__ A,
                                                 const unsigned short* __restrict__ Bt,
                                                 TC* __restrict__ C,
                                                 int M, int K, int Ntot) {
    __shared__ unsigned short As[128][40];   // +8 pad: 2-way LDS conflicts only
    __shared__ unsigned short Bs[128][40];
    int t = threadIdx.x;
    int m0 = blockIdx.x * 128;
    int n0 = blockIdx.y * 128;
    int wave = t >> 6, lane = t & 63;
    int wm = (wave >> 1) * 64, wn = (wave & 1) * 64;
    int lrow = lane & 15;   // row/col within 16-tile
    int lq = lane >> 4;     // quad: k offset = lq*8, C row base = lq*4

    f32x4 acc[4][4];
#pragma unroll
    for (int i = 0; i < 4; i++)
#pragma unroll
        for (int j = 0; j < 4; j++)
            acc[i][j] = (f32x4){0.f, 0.f, 0.f, 0.f};

    // staging: 512 chunks of 16B (8 bf16); chunk c -> row=c>>2, q=c&3
    int r0 = t >> 2, q0 = t & 3;
    int c1 = t + 256;
    int r1 = c1 >> 2, q1 = c1 & 3;

    for (int k0 = 0; k0 < K; k0 += 32) {
        int4 av0 = {0, 0, 0, 0}, av1 = {0, 0, 0, 0};
        if (m0 + r0 < M) av0 = *(const int4*)&A[(size_t)(m0 + r0) * K + k0 + q0 * 8];
        if (m0 + r1 < M) av1 = *(const int4*)&A[(size_t)(m0 + r1) * K + k0 + q1 * 8];
        int4 bv0 = *(const int4*)&Bt[(size_t)(n0 + r0) * K + k0 + q0 * 8];
        int4 bv1 = *(const int4*)&Bt[(size_t)(n0 + r1) * K + k0 + q1 * 8];
        __syncthreads();
        *(int4*)&As[r0][q0 * 8] = av0;
        *(int4*)&As[r1][q1 * 8] = av1;
        *(int4*)&Bs[r0][q0 * 8] = bv0;
        *(int4*)&Bs[r1][q1 * 8] = bv1;
        __syncthreads();
        short8 af[4], bfr[4];
#pragma unroll
        for (int i = 0; i < 4; i++) {
            af[i] = *(const short8*)&As[wm + i * 16 + lrow][lq * 8];
            bfr[i] = *(const short8*)&Bs[wn + i * 16 + lrow][lq * 8];
        }
#pragma unroll
        for (int i = 0; i < 4; i++)
#pragma unroll
            for (int j = 0; j < 4; j++)
                acc[i][j] = __builtin_amdgcn_mfma_f32_16x16x32_bf16(af[i], bfr[j], acc[i][j], 0, 0, 0);
    }
    // C/D layout: col = lane&15, row = (lane>>4)*4 + reg  [verified m89/m91]
#pragma unroll
    for (int i = 0; i < 4; i++) {
#pragma unroll
        for (int reg = 0; reg < 4; reg++) {
            int gm = m0 + wm + i * 16 + lq * 4 + reg;
            if (gm < M) {
#pragma unroll
                for (int j = 0; j < 4; j++) {
                    int gn = n0 + wn + j * 16 + lrow;
                    storeC(C, (size_t)gm * Ntot + gn, acc[i][j][reg]);
                }
            }
        }
    }
}

// ------------------------------------------------- attention score pre-dots
__global__ __launch_bounds__(256) void sdot_kernel(const float* __restrict__ xp,
                                                   const float* __restrict__ a_src,
                                                   const float* __restrict__ a_dst,
                                                   float* __restrict__ s_src,
                                                   float* __restrict__ s_dst) {
    __shared__ float r1[256];
    __shared__ float r2[256];
    int n = blockIdx.x, t = threadIdx.x;
    float v = xp[(size_t)n * H + t];
    r1[t] = v * a_src[t];
    r2[t] = v * a_dst[t];
    __syncthreads();
    for (int off = 128; off > 0; off >>= 1) {
        if (t < off) { r1[t] += r1[t + off]; r2[t] += r2[t + off]; }
        __syncthreads();
    }
    if (t == 0) { s_src[n] = r1[0]; s_dst[n] = r2[0]; }
}

// --------------------------------------------------------- GAT aggregation
// out is bf16 (feeds next GEMM's A operand only)
__global__ __launch_bounds__(256) void gat_agg(const float* __restrict__ xp,
                                               const float* __restrict__ s_src,
                                               const float* __restrict__ s_dst,
                                               const int* __restrict__ indptr,
                                               const int* __restrict__ eids,
                                               const int* __restrict__ src_arr,
                                               const float* __restrict__ bias,
                                               unsigned short* __restrict__ out) {
    __shared__ float red[256];
    __shared__ int   sL[128];
    __shared__ float wL[128];
    __shared__ float s_m, s_dinv;
    int n = blockIdx.x, t = threadIdx.x;
    int start = indptr[n];
    int deg = indptr[n + 1] - start;
    float sdn = s_dst[n];

    // pass 1: max
    float lm = -1e30f;
    for (int i = t; i < deg; i += 256) {
        int e = eids[start + i];
        int s = (e < N_EDGES) ? src_arr[e] : (e - N_EDGES);
        float v = s_src[s] + sdn;
        v = (v >= 0.f) ? v : NEG_SLOPE * v;
        lm = fmaxf(lm, v);
    }
    red[t] = lm;
    __syncthreads();
    for (int off = 128; off > 0; off >>= 1) {
        if (t < off) red[t] = fmaxf(red[t], red[t + off]);
        __syncthreads();
    }
    if (t == 0) s_m = red[0];
    __syncthreads();
    float m = s_m;
    __syncthreads();

    // pass 2: denom
    float ls = 0.f;
    for (int i = t; i < deg; i += 256) {
        int e = eids[start + i];
        int s = (e < N_EDGES) ? src_arr[e] : (e - N_EDGES);
        float v = s_src[s] + sdn;
        v = (v >= 0.f) ? v : NEG_SLOPE * v;
        ls += expf(v - m);
    }
    red[t] = ls;
    __syncthreads();
    for (int off = 128; off > 0; off >>= 1) {
        if (t < off) red[t] += red[t + off];
        __syncthreads();
    }
    if (t == 0) s_dinv = 1.f / red[0];
    __syncthreads();
    float dinv = s_dinv;

    // pass 3: weighted gather, chunks of 128 edges
    float acc = 0.f;
    for (int base = 0; base < deg; base += 128) {
        int cnt = min(128, deg - base);
        __syncthreads();
        if (t < cnt) {
            int e = eids[start + base + t];
            int s = (e < N_EDGES) ? src_arr[e] : (e - N_EDGES);
            float v = s_src[s] + sdn;
            v = (v >= 0.f) ? v : NEG_SLOPE * v;
            sL[t] = s;
            wL[t] = expf(v - m) * dinv;
        }
        __syncthreads();
        for (int j = 0; j < cnt; j++)
            acc += wL[j] * xp[(size_t)sL[j] * H + t];
    }
    float o = acc + bias[t];
    out[(size_t)n * H + t] = f2bf((o > 0.f) ? o : 0.f);   // relu wrapper
}

// ------------------------------------------------------------- GRU gates
// gates [cnt][768] bf16 (r cols 0..255, z 256..511, n 512..767) -> h [*, 256] fp32
__global__ __launch_bounds__(256) void gru_gates(const unsigned short* __restrict__ gates,
                                                 const float* __restrict__ b_ih,
                                                 const float* __restrict__ b_hh,
                                                 float* __restrict__ hout,
                                                 int nodeBase, int nodeCount) {
    int n = blockIdx.x;
    if (n >= nodeCount) return;
    int t = threadIdx.x;
    size_t row = (size_t)n * 768;
    float ir = bf2f(gates[row + t]);
    float iz = bf2f(gates[row + 256 + t]);
    float in_ = bf2f(gates[row + 512 + t]);
    float r = 1.f / (1.f + expf(-(ir + b_ih[t] + b_hh[t])));
    float z = 1.f / (1.f + expf(-(iz + b_ih[256 + t] + b_hh[256 + t])));
    float nn = tanhf(in_ + b_ih[512 + t] + r * b_hh[512 + t]);
    hout[(size_t)(nodeBase + n) * H + t] = (1.f - z) * nn;
}

// --------------------------------------------------------------- pooling
__global__ __launch_bounds__(256) void pool_kernel(const float* __restrict__ h,
                                                   const int* __restrict__ batch,
                                                   float* __restrict__ pooled) {
    int n = blockIdx.x, t = threadIdx.x;
    int g = batch[n];
    atomicAdd(&pooled[(size_t)g * H + t], h[(size_t)n * H + t]);
}

__global__ __launch_bounds__(256) void super_kernel(const float* __restrict__ pooled,
                                                    const float* __restrict__ Wf,
                                                    const float* __restrict__ bf,
                                                    float* __restrict__ sup) {
    __shared__ float smean[256];
    int t = threadIdx.x;
    float s = 0.f;
    for (int g = 0; g < G_GRAPHS; g++) s += pooled[(size_t)g * H + t];
    smean[t] = s / (float)G_GRAPHS;
    __syncthreads();
    float acc = 0.f;
    for (int k = 0; k < H; k++) acc += smean[k] * Wf[(size_t)t * H + k];
    acc += bf[t];
    sup[t] = fmaxf(acc, 0.f);
}

__global__ __launch_bounds__(256) void writeout(const float* __restrict__ pooled,
                                                const float* __restrict__ sup,
                                                float* __restrict__ out) {
    int idx = blockIdx.x * 256 + threadIdx.x;   // G*2H = 65536
    int g = idx >> 9, c = idx & 511;
    out[idx] = (c < H) ? pooled[(size_t)g * H + c] : sup[c - H];
}

// ---------------------------------------------------------------- launcher
extern "C" void kernel_launch(void* const* d_in, const int* in_sizes, int n_in,
                              void* d_out, int out_size, void* d_ws, size_t ws_size,
                              hipStream_t stream) {
    const float* x      = (const float*)d_in[0];
    const int*   ei     = (const int*)d_in[1];
    const int*   batch  = (const int*)d_in[2];
    const float* W0     = (const float*)d_in[3];
    const float* a_src0 = (const float*)d_in[4];
    const float* a_dst0 = (const float*)d_in[5];
    const float* b0     = (const float*)d_in[6];
    const float* W1     = (const float*)d_in[7];
    const float* a_src1 = (const float*)d_in[8];
    const float* a_dst1 = (const float*)d_in[9];
    const float* b1     = (const float*)d_in[10];
    const float* W_ih   = (const float*)d_in[11];
    // d_in[12] = W_hh unused (h0 = 0)
    const float* b_ih   = (const float*)d_in[13];
    const float* b_hh   = (const float*)d_in[14];
    const float* Wf     = (const float*)d_in[15];
    const float* bf     = (const float*)d_in[16];
    float* out = (float*)d_out;

    char* p = (char*)d_ws;
    auto alloc = [&](size_t bytes) -> void* {
        void* r = (void*)p;
        p += (bytes + 255) & ~(size_t)255;
        return r;
    };
    float*          xp     = (float*)alloc((size_t)N_NODES * H * 4);          // xp0/xp1, later h_gru
    unsigned short* h_bf   = (unsigned short*)alloc((size_t)N_NODES * H * 2); // gat out (bf16)
    unsigned short* x_bf   = (unsigned short*)alloc((size_t)N_NODES * IN_CH * 2);
    unsigned short* gatesC = (unsigned short*)alloc((size_t)GRU_CHUNK * 3 * H * 2);
    unsigned short* W0t    = (unsigned short*)alloc((size_t)H * IN_CH * 2);
    unsigned short* W1t    = (unsigned short*)alloc((size_t)H * H * 2);
    unsigned short* Wih_bf = (unsigned short*)alloc((size_t)3 * H * H * 2);
    float* s_src  = (float*)alloc((size_t)N_NODES * 4);
    float* s_dst  = (float*)alloc((size_t)N_NODES * 4);
    int*   counts = (int*)alloc((size_t)N_NODES * 4);
    int*   incl   = (int*)alloc((size_t)N_NODES * 4);
    int*   indptr = (int*)alloc((size_t)(N_NODES + 1) * 4);
    int*   cursor = (int*)alloc((size_t)N_NODES * 4);
    int*   eids   = (int*)alloc((size_t)ET * 4);
    int*   bSums  = (int*)alloc(256 * 4);
    int*   bOff   = (int*)alloc(256 * 4);
    float* pooled = (float*)alloc((size_t)G_GRAPHS * H * 4);
    float* sup    = (float*)alloc((size_t)H * 4);

    const int SB = (N_NODES + 255) / 256;            // 196
    // CSR build
    init_counts<<<SB, 256, 0, stream>>>(counts);
    hist_kernel<<<(N_EDGES + 255) / 256, 256, 0, stream>>>(ei, counts);
    scan_block<<<SB, 256, 0, stream>>>(counts, incl, bSums);
    scan_sums<<<1, 256, 0, stream>>>(bSums, bOff, SB);
    scan_finalize<<<SB, 256, 0, stream>>>(incl, bOff, indptr, cursor);
    scatter_kernel<<<(ET + 255) / 256, 256, 0, stream>>>(ei, cursor, eids);

    // weight conversions
    convert_f2bf<<<((N_NODES * IN_CH) + 255) / 256, 256, 0, stream>>>(x, x_bf, N_NODES * IN_CH);
    transpose_f2bf<<<((IN_CH * H) + 255) / 256, 256, 0, stream>>>(W0, W0t, IN_CH, H);
    transpose_f2bf<<<((H * H) + 255) / 256, 256, 0, stream>>>(W1, W1t, H, H);
    convert_f2bf<<<((3 * H * H) + 255) / 256, 256, 0, stream>>>(W_ih, Wih_bf, 3 * H * H);

    const int MB = (N_NODES + 127) / 128;            // 391
    // GAT layer 0: xp = x @ W0
    gemm_mfma<float><<<dim3(MB, H / 128), 256, 0, stream>>>(x_bf, W0t, xp, N_NODES, IN_CH, H);
    sdot_kernel<<<N_NODES, 256, 0, stream>>>(xp, a_src0, a_dst0, s_src, s_dst);
    gat_agg<<<N_NODES, 256, 0, stream>>>(xp, s_src, s_dst, indptr, eids, ei, b0, h_bf);
    // GAT layer 1: xp = h @ W1
    gemm_mfma<float><<<dim3(MB, H / 128), 256, 0, stream>>>(h_bf, W1t, xp, N_NODES, H, H);
    sdot_kernel<<<N_NODES, 256, 0, stream>>>(xp, a_src1, a_dst1, s_src, s_dst);
    gat_agg<<<N_NODES, 256, 0, stream>>>(xp, s_src, s_dst, indptr, eids, ei, b1, h_bf);
    // GRU: gates = h2 @ W_ih^T (chunked), then gate combine -> xp (reused as h_gru)
    for (int base = 0; base < N_NODES; base += GRU_CHUNK) {
        int cnt = min(GRU_CHUNK, N_NODES - base);
        gemm_mfma<unsigned short><<<dim3((cnt + 127) / 128, (3 * H) / 128), 256, 0, stream>>>(
            h_bf + (size_t)base * H, Wih_bf, gatesC, cnt, H, 3 * H);
        gru_gates<<<cnt, 256, 0, stream>>>(gatesC, b_ih, b_hh, xp, base, cnt);
    }
    // pooling + super node
    hipMemsetAsync(pooled, 0, (size_t)G_GRAPHS * H * 4, stream);
    pool_kernel<<<N_NODES, 256, 0, stream>>>(xp, batch, pooled);
    super_kernel<<<1, 256, 0, stream>>>(pooled, Wf, bf, sup);
    writeout<<<(G_GRAPHS * 2 * H) / 256, 256, 0, stream>>>(pooled, sup, out);
}

// Round 3
// 514.310 us; speedup vs baseline: 2.3754x; 1.6567x over previous
//
#include <hip/hip_runtime.h>
#include <math.h>

#define N_NODES 50000
#define N_EDGES 800000
#define ET (N_EDGES + N_NODES)   // 850000 with self loops
#define IN_CH 128
#define H 256
#define G_GRAPHS 128
#define NEG_SLOPE 0.2f
#define GRU_CHUNK 25000

typedef __attribute__((ext_vector_type(8))) short short8;
typedef __attribute__((ext_vector_type(4))) float f32x4;
typedef unsigned short u16;

__device__ inline u16 f2bf(float v) {
    unsigned u = __float_as_uint(v);
    unsigned r = (u + 0x7FFFu + ((u >> 16) & 1u)) >> 16;
    return (u16)r;
}
__device__ inline float bf2f(u16 v) {
    return __uint_as_float(((unsigned)v) << 16);
}

// ---------------------------------------------------------------- CSR build
__global__ __launch_bounds__(256) void init_counts(int* __restrict__ counts) {
    int i = blockIdx.x * 256 + threadIdx.x;
    if (i < N_NODES) counts[i] = 1;   // self loop
}

__global__ __launch_bounds__(256) void hist_kernel(const int* __restrict__ ei,
                                                   int* __restrict__ counts) {
    int e = blockIdx.x * 256 + threadIdx.x;
    if (e < N_EDGES) atomicAdd(&counts[ei[N_EDGES + e]], 1);
}

__global__ __launch_bounds__(256) void scan_block(const int* __restrict__ in,
                                                  int* __restrict__ incl,
                                                  int* __restrict__ blockSums) {
    __shared__ int s[256];
    int t = threadIdx.x;
    int i = blockIdx.x * 256 + t;
    int v = (i < N_NODES) ? in[i] : 0;
    s[t] = v;
    __syncthreads();
    for (int off = 1; off < 256; off <<= 1) {
        int x = 0;
        if (t >= off) x = s[t - off];
        __syncthreads();
        if (t >= off) s[t] += x;
        __syncthreads();
    }
    if (i < N_NODES) incl[i] = s[t];
    if (t == 255) blockSums[blockIdx.x] = s[255];
}

__global__ __launch_bounds__(256) void scan_sums(const int* __restrict__ blockSums,
                                                 int* __restrict__ blockOff, int nb) {
    __shared__ int s[256];
    int t = threadIdx.x;
    int v = (t < nb) ? blockSums[t] : 0;
    s[t] = v;
    __syncthreads();
    for (int off = 1; off < 256; off <<= 1) {
        int x = 0;
        if (t >= off) x = s[t - off];
        __syncthreads();
        if (t >= off) s[t] += x;
        __syncthreads();
    }
    if (t < nb) blockOff[t] = s[t] - v;   // exclusive
}

__global__ __launch_bounds__(256) void scan_finalize(const int* __restrict__ incl,
                                                     const int* __restrict__ blockOff,
                                                     int* __restrict__ indptr,
                                                     int* __restrict__ cursor) {
    int i = blockIdx.x * 256 + threadIdx.x;
    if (i < N_NODES) {
        int v = incl[i] + blockOff[i >> 8];
        indptr[i + 1] = v;
        if (i + 1 < N_NODES) cursor[i + 1] = v;
    }
    if (i == 0) { indptr[0] = 0; cursor[0] = 0; }
}

__global__ __launch_bounds__(256) void scatter_kernel(const int* __restrict__ ei,
                                                      int* __restrict__ cursor,
                                                      int* __restrict__ eids) {
    int e = blockIdx.x * 256 + threadIdx.x;
    if (e < ET) {
        int dst = (e < N_EDGES) ? ei[N_EDGES + e] : (e - N_EDGES);
        int pos = atomicAdd(&cursor[dst], 1);
        eids[pos] = e;
    }
}

// ---------------------------------------------------------------- converts
__global__ __launch_bounds__(256) void convert_f2bf4(const float* __restrict__ in,
                                                     u16* __restrict__ out, int n4) {
    int i = blockIdx.x * 256 + threadIdx.x;
    if (i < n4) {
        float4 v = *(const float4*)&in[i * 4];
        ushort4 o;
        o.x = f2bf(v.x); o.y = f2bf(v.y); o.z = f2bf(v.z); o.w = f2bf(v.w);
        *(ushort4*)&out[i * 4] = o;
    }
}

// W [K][Nc] fp32 row-major -> Wt [Nc][K] bf16
__global__ __launch_bounds__(256) void transpose_f2bf(const float* __restrict__ W,
                                                      u16* __restrict__ Wt,
                                                      int K, int Nc) {
    int idx = blockIdx.x * 256 + threadIdx.x;
    if (idx < K * Nc) {
        int k = idx / Nc, n = idx % Nc;
        Wt[(size_t)n * K + k] = f2bf(W[idx]);
    }
}

// ------------------------------------------------------------ MFMA GEMM
// C[M,Ntot] = A[M,K](bf16) @ Bt[Ntot,K]^T (bf16), fp32 acc, bf16 out.
// 128x128 tile, BK=32, 256 thr = 4 waves (2x2 of 64x64), 4x4 16x16x32 tiles/wave.
__global__ __launch_bounds__(256) void gemm_mfma(const u16* __restrict__ A,
                                                 const u16* __restrict__ Bt,
                                                 u16* __restrict__ C,
                                                 int M, int K, int Ntot) {
    __shared__ u16 As[128][40];   // +8 pad
    __shared__ u16 Bs[128][40];
    int t = threadIdx.x;
    int m0 = blockIdx.x * 128;
    int n0 = blockIdx.y * 128;
    int wave = t >> 6, lane = t & 63;
    int wm = (wave >> 1) * 64, wn = (wave & 1) * 64;
    int lrow = lane & 15;
    int lq = lane >> 4;

    f32x4 acc[4][4];
#pragma unroll
    for (int i = 0; i < 4; i++)
#pragma unroll
        for (int j = 0; j < 4; j++)
            acc[i][j] = (f32x4){0.f, 0.f, 0.f, 0.f};

    int r0 = t >> 2, q0 = t & 3;
    int c1 = t + 256;
    int r1 = c1 >> 2, q1 = c1 & 3;

    for (int k0 = 0; k0 < K; k0 += 32) {
        int4 av0 = {0, 0, 0, 0}, av1 = {0, 0, 0, 0};
        if (m0 + r0 < M) av0 = *(const int4*)&A[(size_t)(m0 + r0) * K + k0 + q0 * 8];
        if (m0 + r1 < M) av1 = *(const int4*)&A[(size_t)(m0 + r1) * K + k0 + q1 * 8];
        int4 bv0 = *(const int4*)&Bt[(size_t)(n0 + r0) * K + k0 + q0 * 8];
        int4 bv1 = *(const int4*)&Bt[(size_t)(n0 + r1) * K + k0 + q1 * 8];
        __syncthreads();
        *(int4*)&As[r0][q0 * 8] = av0;
        *(int4*)&As[r1][q1 * 8] = av1;
        *(int4*)&Bs[r0][q0 * 8] = bv0;
        *(int4*)&Bs[r1][q1 * 8] = bv1;
        __syncthreads();
        short8 af[4], bfr[4];
#pragma unroll
        for (int i = 0; i < 4; i++) {
            af[i] = *(const short8*)&As[wm + i * 16 + lrow][lq * 8];
            bfr[i] = *(const short8*)&Bs[wn + i * 16 + lrow][lq * 8];
        }
#pragma unroll
        for (int i = 0; i < 4; i++)
#pragma unroll
            for (int j = 0; j < 4; j++)
                acc[i][j] = __builtin_amdgcn_mfma_f32_16x16x32_bf16(af[i], bfr[j], acc[i][j], 0, 0, 0);
    }
    // C/D layout: col = lane&15, row = (lane>>4)*4 + reg
#pragma unroll
    for (int i = 0; i < 4; i++) {
#pragma unroll
        for (int reg = 0; reg < 4; reg++) {
            int gm = m0 + wm + i * 16 + lq * 4 + reg;
            if (gm < M) {
#pragma unroll
                for (int j = 0; j < 4; j++) {
                    int gn = n0 + wn + j * 16 + lrow;
                    C[(size_t)gm * Ntot + gn] = f2bf(acc[i][j][reg]);
                }
            }
        }
    }
}

// ------------------------------------------------- attention score pre-dots
// wave per node; lane covers 4 cols
__global__ __launch_bounds__(256) void sdot_wave(const u16* __restrict__ xp,
                                                 const float* __restrict__ a_src,
                                                 const float* __restrict__ a_dst,
                                                 float* __restrict__ s_src,
                                                 float* __restrict__ s_dst) {
    int wave = threadIdx.x >> 6, lane = threadIdx.x & 63;
    int n = blockIdx.x * 4 + wave;
    int col = lane << 2;
    ushort4 v = *(const ushort4*)&xp[(size_t)n * H + col];
    float4 a1 = *(const float4*)&a_src[col];
    float4 a2 = *(const float4*)&a_dst[col];
    float x0 = bf2f(v.x), x1 = bf2f(v.y), x2 = bf2f(v.z), x3 = bf2f(v.w);
    float d1 = x0 * a1.x + x1 * a1.y + x2 * a1.z + x3 * a1.w;
    float d2 = x0 * a2.x + x1 * a2.y + x2 * a2.z + x3 * a2.w;
#pragma unroll
    for (int off = 32; off; off >>= 1) {
        d1 += __shfl_xor(d1, off);
        d2 += __shfl_xor(d2, off);
    }
    if (lane == 0) { s_src[n] = d1; s_dst[n] = d2; }
}

// --------------------------------------------------------- GAT aggregation
// wave per node (4 nodes / 256-block); bf16 gather, bf16 out (+bias, relu)
__global__ __launch_bounds__(256) void gat_agg_wave(const u16* __restrict__ xp,
                                                    const float* __restrict__ s_src,
                                                    const float* __restrict__ s_dst,
                                                    const int* __restrict__ indptr,
                                                    const int* __restrict__ eids,
                                                    const int* __restrict__ src_arr,
                                                    const float* __restrict__ bias,
                                                    u16* __restrict__ out) {
    int wave = threadIdx.x >> 6, lane = threadIdx.x & 63;
    int n = blockIdx.x * 4 + wave;
    int start = indptr[n];
    int deg = indptr[n + 1] - start;
    float sdn = s_dst[n];
    int col = lane << 2;
    float a0 = 0.f, a1 = 0.f, a2 = 0.f, a3 = 0.f;

    if (deg <= 64) {
        // fast path: one edge per lane
        int s = 0;
        float v = -1e30f;
        if (lane < deg) {
            int e = eids[start + lane];
            s = (e < N_EDGES) ? src_arr[e] : (e - N_EDGES);
            float u = s_src[s] + sdn;
            v = (u >= 0.f) ? u : NEG_SLOPE * u;
        }
        float m = v;
#pragma unroll
        for (int off = 32; off; off >>= 1) m = fmaxf(m, __shfl_xor(m, off));
        float pw = (lane < deg) ? expf(v - m) : 0.f;
        float dsum = pw;
#pragma unroll
        for (int off = 32; off; off >>= 1) dsum += __shfl_xor(dsum, off);
        float w = pw * (1.f / dsum);
#pragma unroll 2
        for (int j = 0; j < deg; j++) {
            int sj = __shfl(s, j);
            float wj = __shfl(w, j);
            ushort4 rv = *(const ushort4*)&xp[(size_t)sj * H + col];
            a0 += wj * bf2f(rv.x);
            a1 += wj * bf2f(rv.y);
            a2 += wj * bf2f(rv.z);
            a3 += wj * bf2f(rv.w);
        }
    } else {
        // general path (rare): 3 passes
        float m = -1e30f;
        for (int i = lane; i < deg; i += 64) {
            int e = eids[start + i];
            int s = (e < N_EDGES) ? src_arr[e] : (e - N_EDGES);
            float u = s_src[s] + sdn;
            u = (u >= 0.f) ? u : NEG_SLOPE * u;
            m = fmaxf(m, u);
        }
#pragma unroll
        for (int off = 32; off; off >>= 1) m = fmaxf(m, __shfl_xor(m, off));
        float dsum = 0.f;
        for (int i = lane; i < deg; i += 64) {
            int e = eids[start + i];
            int s = (e < N_EDGES) ? src_arr[e] : (e - N_EDGES);
            float u = s_src[s] + sdn;
            u = (u >= 0.f) ? u : NEG_SLOPE * u;
            dsum += expf(u - m);
        }
#pragma unroll
        for (int off = 32; off; off >>= 1) dsum += __shfl_xor(dsum, off);
        float dinv = 1.f / dsum;
        for (int base = 0; base < deg; base += 64) {
            int cnt = min(64, deg - base);
            int s = 0; float w = 0.f;
            if (lane < cnt) {
                int e = eids[start + base + lane];
                s = (e < N_EDGES) ? src_arr[e] : (e - N_EDGES);
                float u = s_src[s] + sdn;
                u = (u >= 0.f) ? u : NEG_SLOPE * u;
                w = expf(u - m) * dinv;
            }
            for (int j = 0; j < cnt; j++) {
                int sj = __shfl(s, j);
                float wj = __shfl(w, j);
                ushort4 rv = *(const ushort4*)&xp[(size_t)sj * H + col];
                a0 += wj * bf2f(rv.x);
                a1 += wj * bf2f(rv.y);
                a2 += wj * bf2f(rv.z);
                a3 += wj * bf2f(rv.w);
            }
        }
    }
    float4 bv = *(const float4*)&bias[col];
    ushort4 o;
    o.x = f2bf(fmaxf(a0 + bv.x, 0.f));
    o.y = f2bf(fmaxf(a1 + bv.y, 0.f));
    o.z = f2bf(fmaxf(a2 + bv.z, 0.f));
    o.w = f2bf(fmaxf(a3 + bv.w, 0.f));
    *(ushort4*)&out[(size_t)n * H + col] = o;
}

// ------------------------------------------------- GRU gates + pooling (fused)
// 16 consecutive nodes per block; batch is sorted -> few atomic flushes.
__global__ __launch_bounds__(256) void gru_gates_pool(const u16* __restrict__ gates,
                                                      const float* __restrict__ b_ih,
                                                      const float* __restrict__ b_hh,
                                                      const int* __restrict__ batch,
                                                      float* __restrict__ pooled,
                                                      int nodeBase, int nodeCount) {
    int t = threadIdx.x;
    int i0 = blockIdx.x * 16;
    if (i0 >= nodeCount) return;
    float bir = b_ih[t], biz = b_ih[256 + t], bin_ = b_ih[512 + t];
    float bhr = b_hh[t], bhz = b_hh[256 + t], bhn = b_hh[512 + t];
    int iend = min(16, nodeCount - i0);
    float acc = 0.f;
    int cur_g = batch[nodeBase + i0];
    for (int i = 0; i < iend; i++) {
        size_t row = (size_t)(i0 + i) * 768;
        float ir = bf2f(gates[row + t]);
        float iz = bf2f(gates[row + 256 + t]);
        float in_ = bf2f(gates[row + 512 + t]);
        float r = 1.f / (1.f + expf(-(ir + bir + bhr)));
        float z = 1.f / (1.f + expf(-(iz + biz + bhz)));
        float nn = tanhf(in_ + bin_ + r * bhn);
        float h = (1.f - z) * nn;
        int g = batch[nodeBase + i0 + i];
        if (g != cur_g) {
            atomicAdd(&pooled[(size_t)cur_g * H + t], acc);
            acc = 0.f;
            cur_g = g;
        }
        acc += h;
    }
    atomicAdd(&pooled[(size_t)cur_g * H + t], acc);
}

// --------------------------------------------------------------- super node
__global__ __launch_bounds__(256) void super_kernel(const float* __restrict__ pooled,
                                                    const float* __restrict__ Wf,
                                                    const float* __restrict__ bf,
                                                    float* __restrict__ sup) {
    __shared__ float smean[256];
    int t = threadIdx.x;
    float s = 0.f;
    for (int g = 0; g < G_GRAPHS; g++) s += pooled[(size_t)g * H + t];
    smean[t] = s / (float)G_GRAPHS;
    __syncthreads();
    float acc = 0.f;
    for (int k = 0; k < H; k++) acc += smean[k] * Wf[(size_t)t * H + k];
    acc += bf[t];
    sup[t] = fmaxf(acc, 0.f);
}

__global__ __launch_bounds__(256) void writeout(const float* __restrict__ pooled,
                                                const float* __restrict__ sup,
                                                float* __restrict__ out) {
    int idx = blockIdx.x * 256 + threadIdx.x;   // G*2H = 65536
    int g = idx >> 9, c = idx & 511;
    out[idx] = (c < H) ? pooled[(size_t)g * H + c] : sup[c - H];
}

// ---------------------------------------------------------------- launcher
extern "C" void kernel_launch(void* const* d_in, const int* in_sizes, int n_in,
                              void* d_out, int out_size, void* d_ws, size_t ws_size,
                              hipStream_t stream) {
    const float* x      = (const float*)d_in[0];
    const int*   ei     = (const int*)d_in[1];
    const int*   batch  = (const int*)d_in[2];
    const float* W0     = (const float*)d_in[3];
    const float* a_src0 = (const float*)d_in[4];
    const float* a_dst0 = (const float*)d_in[5];
    const float* b0     = (const float*)d_in[6];
    const float* W1     = (const float*)d_in[7];
    const float* a_src1 = (const float*)d_in[8];
    const float* a_dst1 = (const float*)d_in[9];
    const float* b1     = (const float*)d_in[10];
    const float* W_ih   = (const float*)d_in[11];
    // d_in[12] = W_hh unused (h0 = 0)
    const float* b_ih   = (const float*)d_in[13];
    const float* b_hh   = (const float*)d_in[14];
    const float* Wf     = (const float*)d_in[15];
    const float* bf     = (const float*)d_in[16];
    float* out = (float*)d_out;

    char* p = (char*)d_ws;
    auto alloc = [&](size_t bytes) -> void* {
        void* r = (void*)p;
        p += (bytes + 255) & ~(size_t)255;
        return r;
    };
    u16*   xp_bf  = (u16*)alloc((size_t)N_NODES * H * 2);
    u16*   h_bf   = (u16*)alloc((size_t)N_NODES * H * 2);
    u16*   x_bf   = (u16*)alloc((size_t)N_NODES * IN_CH * 2);
    u16*   gatesC = (u16*)alloc((size_t)GRU_CHUNK * 3 * H * 2);
    u16*   W0t    = (u16*)alloc((size_t)H * IN_CH * 2);
    u16*   W1t    = (u16*)alloc((size_t)H * H * 2);
    u16*   Wih_bf = (u16*)alloc((size_t)3 * H * H * 2);
    float* s_src  = (float*)alloc((size_t)N_NODES * 4);
    float* s_dst  = (float*)alloc((size_t)N_NODES * 4);
    int*   counts = (int*)alloc((size_t)N_NODES * 4);
    int*   incl   = (int*)alloc((size_t)N_NODES * 4);
    int*   indptr = (int*)alloc((size_t)(N_NODES + 1) * 4);
    int*   cursor = (int*)alloc((size_t)N_NODES * 4);
    int*   eids   = (int*)alloc((size_t)ET * 4);
    int*   bSums  = (int*)alloc(256 * 4);
    int*   bOff   = (int*)alloc(256 * 4);
    float* pooled = (float*)alloc((size_t)G_GRAPHS * H * 4);
    float* sup    = (float*)alloc((size_t)H * 4);

    const int SB = (N_NODES + 255) / 256;            // 196
    // CSR build
    init_counts<<<SB, 256, 0, stream>>>(counts);
    hist_kernel<<<(N_EDGES + 255) / 256, 256, 0, stream>>>(ei, counts);
    scan_block<<<SB, 256, 0, stream>>>(counts, incl, bSums);
    scan_sums<<<1, 256, 0, stream>>>(bSums, bOff, SB);
    scan_finalize<<<SB, 256, 0, stream>>>(incl, bOff, indptr, cursor);
    scatter_kernel<<<(ET + 255) / 256, 256, 0, stream>>>(ei, cursor, eids);

    // weight/input conversions
    convert_f2bf4<<<((N_NODES * IN_CH / 4) + 255) / 256, 256, 0, stream>>>(x, x_bf, N_NODES * IN_CH / 4);
    transpose_f2bf<<<((IN_CH * H) + 255) / 256, 256, 0, stream>>>(W0, W0t, IN_CH, H);
    transpose_f2bf<<<((H * H) + 255) / 256, 256, 0, stream>>>(W1, W1t, H, H);
    convert_f2bf4<<<((3 * H * H / 4) + 255) / 256, 256, 0, stream>>>(W_ih, Wih_bf, 3 * H * H / 4);

    const int MB = (N_NODES + 127) / 128;            // 391
    const int WB = N_NODES / 4;                       // 12500 (wave-per-node grids)
    // GAT layer 0
    gemm_mfma<<<dim3(MB, H / 128), 256, 0, stream>>>(x_bf, W0t, xp_bf, N_NODES, IN_CH, H);
    sdot_wave<<<WB, 256, 0, stream>>>(xp_bf, a_src0, a_dst0, s_src, s_dst);
    gat_agg_wave<<<WB, 256, 0, stream>>>(xp_bf, s_src, s_dst, indptr, eids, ei, b0, h_bf);
    // GAT layer 1
    gemm_mfma<<<dim3(MB, H / 128), 256, 0, stream>>>(h_bf, W1t, xp_bf, N_NODES, H, H);
    sdot_wave<<<WB, 256, 0, stream>>>(xp_bf, a_src1, a_dst1, s_src, s_dst);
    gat_agg_wave<<<WB, 256, 0, stream>>>(xp_bf, s_src, s_dst, indptr, eids, ei, b1, h_bf);
    // GRU (chunked) + fused pooling
    hipMemsetAsync(pooled, 0, (size_t)G_GRAPHS * H * 4, stream);
    for (int base = 0; base < N_NODES; base += GRU_CHUNK) {
        int cnt = min(GRU_CHUNK, N_NODES - base);
        gemm_mfma<<<dim3((cnt + 127) / 128, (3 * H) / 128), 256, 0, stream>>>(
            h_bf + (size_t)base * H, Wih_bf, gatesC, cnt, H, 3 * H);
        gru_gates_pool<<<(cnt + 15) / 16, 256, 0, stream>>>(gatesC, b_ih, b_hh, batch, pooled, base, cnt);
    }
    // super node + writeout
    super_kernel<<<1, 256, 0, stream>>>(pooled, Wf, bf, sup);
    writeout<<<(G_GRAPHS * 2 * H) / 256, 256, 0, stream>>>(pooled, sup, out);
}

// Round 4
// 488.287 us; speedup vs baseline: 2.5020x; 1.0533x over previous
//
#include <hip/hip_runtime.h>
#include <math.h>

#define N_NODES 50000
#define N_PAD   50176            // 392*128, padded rows for unguarded GEMM A-tiles
#define N_EDGES 800000
#define ET (N_EDGES + N_NODES)   // 850000 with self loops
#define IN_CH 128
#define H 256
#define G_GRAPHS 128
#define NEG_SLOPE 0.2f
#define GRU_CHUNK 25000

typedef __attribute__((ext_vector_type(8))) short short8;
typedef __attribute__((ext_vector_type(4))) float f32x4;
typedef unsigned short u16;

__device__ inline u16 f2bf(float v) {
    unsigned u = __float_as_uint(v);
    unsigned r = (u + 0x7FFFu + ((u >> 16) & 1u)) >> 16;
    return (u16)r;
}
__device__ inline float bf2f(u16 v) {
    return __uint_as_float(((unsigned)v) << 16);
}

// async global->LDS 16B copy (dest must be wave-uniform base + lane*16)
__device__ inline void async_cp16(const u16* g, u16* l) {
    __builtin_amdgcn_global_load_lds(
        (const __attribute__((address_space(1))) unsigned int*)g,
        (__attribute__((address_space(3))) unsigned int*)l,
        16, 0, 0);
}

// ---------------------------------------------------------------- CSR build
__global__ __launch_bounds__(256) void hist_kernel(const int* __restrict__ ei,
                                                   int* __restrict__ counts) {
    int e = blockIdx.x * 256 + threadIdx.x;
    if (e < N_EDGES) atomicAdd(&counts[ei[N_EDGES + e]], 1);
}

// scan over (counts[i] + 1)  — the +1 is the self loop
__global__ __launch_bounds__(256) void scan_block(const int* __restrict__ in,
                                                  int* __restrict__ incl,
                                                  int* __restrict__ blockSums) {
    __shared__ int s[256];
    int t = threadIdx.x;
    int i = blockIdx.x * 256 + t;
    int v = (i < N_NODES) ? (in[i] + 1) : 0;
    s[t] = v;
    __syncthreads();
    for (int off = 1; off < 256; off <<= 1) {
        int x = 0;
        if (t >= off) x = s[t - off];
        __syncthreads();
        if (t >= off) s[t] += x;
        __syncthreads();
    }
    if (i < N_NODES) incl[i] = s[t];
    if (t == 255) blockSums[blockIdx.x] = s[255];
}

__global__ __launch_bounds__(256) void scan_sums(const int* __restrict__ blockSums,
                                                 int* __restrict__ blockOff, int nb) {
    __shared__ int s[256];
    int t = threadIdx.x;
    int v = (t < nb) ? blockSums[t] : 0;
    s[t] = v;
    __syncthreads();
    for (int off = 1; off < 256; off <<= 1) {
        int x = 0;
        if (t >= off) x = s[t - off];
        __syncthreads();
        if (t >= off) s[t] += x;
        __syncthreads();
    }
    if (t < nb) blockOff[t] = s[t] - v;   // exclusive
}

__global__ __launch_bounds__(256) void scan_finalize(const int* __restrict__ incl,
                                                     const int* __restrict__ blockOff,
                                                     int* __restrict__ indptr,
                                                     int* __restrict__ cursor) {
    int i = blockIdx.x * 256 + threadIdx.x;
    if (i < N_NODES) {
        int v = incl[i] + blockOff[i >> 8];
        indptr[i + 1] = v;
        if (i + 1 < N_NODES) cursor[i + 1] = v;
    }
    if (i == 0) { indptr[0] = 0; cursor[0] = 0; }
}

__global__ __launch_bounds__(256) void scatter_kernel(const int* __restrict__ ei,
                                                      int* __restrict__ cursor,
                                                      int* __restrict__ eids) {
    int e = blockIdx.x * 256 + threadIdx.x;
    if (e < ET) {
        int dst = (e < N_EDGES) ? ei[N_EDGES + e] : (e - N_EDGES);
        int pos = atomicAdd(&cursor[dst], 1);
        eids[pos] = e;
    }
}

// ------------------------------------------------- combined conversions
// seg 0: x -> x_bf (vec4), seg 1: W_ih -> Wih_bf (vec4),
// seg 2: W0 -> W0t (transpose), seg 3: W1 -> W1t (transpose)
__global__ __launch_bounds__(256) void prep_kernel(const float* __restrict__ x,
                                                   const float* __restrict__ Wih,
                                                   const float* __restrict__ W0,
                                                   const float* __restrict__ W1,
                                                   u16* __restrict__ x_bf,
                                                   u16* __restrict__ Wih_bf,
                                                   u16* __restrict__ W0t,
                                                   u16* __restrict__ W1t) {
    int i = blockIdx.x * 256 + threadIdx.x;
    int seg = blockIdx.y;
    if (seg == 0) {
        if (i < N_NODES * IN_CH / 4) {
            float4 v = *(const float4*)&x[i * 4];
            ushort4 o = {f2bf(v.x), f2bf(v.y), f2bf(v.z), f2bf(v.w)};
            *(ushort4*)&x_bf[i * 4] = o;
        }
    } else if (seg == 1) {
        if (i < 3 * H * H / 4) {
            float4 v = *(const float4*)&Wih[i * 4];
            ushort4 o = {f2bf(v.x), f2bf(v.y), f2bf(v.z), f2bf(v.w)};
            *(ushort4*)&Wih_bf[i * 4] = o;
        }
    } else if (seg == 2) {
        if (i < IN_CH * H) {
            int k = i / H, n = i % H;
            W0t[(size_t)n * IN_CH + k] = f2bf(W0[i]);
        }
    } else {
        if (i < H * H) {
            int k = i / H, n = i % H;
            W1t[(size_t)n * H + k] = f2bf(W1[i]);
        }
    }
}

// ------------------------------------------------------------ MFMA GEMM
// C[M,Ntot] = A[M,K](bf16) @ Bt[Ntot,K]^T (bf16), fp32 acc, bf16 out.
// 128x128 tile, BK=32, 256 thr = 4 waves. global_load_lds (16B) staging,
// unpadded LDS (layout constraint of global_load_lds). A rows must be
// readable up to tile edge (buffers padded to N_PAD rows).
__global__ __launch_bounds__(256) void gemm_mfma(const u16* __restrict__ A,
                                                 const u16* __restrict__ Bt,
                                                 u16* __restrict__ C,
                                                 int M, int K, int Ntot) {
    __shared__ u16 As[128][32];   // 8 KB, NO pad (global_load_lds contiguity)
    __shared__ u16 Bs[128][32];
    int t = threadIdx.x;
    int m0 = blockIdx.x * 128;
    int n0 = blockIdx.y * 128;
    int wave = t >> 6, lane = t & 63;
    int wm = (wave >> 1) * 64, wn = (wave & 1) * 64;
    int lrow = lane & 15;
    int lq = lane >> 4;

    f32x4 acc[4][4];
#pragma unroll
    for (int i = 0; i < 4; i++)
#pragma unroll
        for (int j = 0; j < 4; j++)
            acc[i][j] = (f32x4){0.f, 0.f, 0.f, 0.f};

    // chunk c (16B) of the 128x32 tile lives at LDS offset c*16;
    // thread t stages chunks t and t+256 -> LDS slot == wave_base + lane*16. ✓
    int r0 = t >> 2, q0 = t & 3;
    int r1 = (t + 256) >> 2, q1 = t & 3;   // (t+256)&3 == t&3
    const u16* gA0 = A + (size_t)(m0 + r0) * K + q0 * 8;
    const u16* gA1 = A + (size_t)(m0 + r1) * K + q1 * 8;
    const u16* gB0 = Bt + (size_t)(n0 + r0) * K + q0 * 8;
    const u16* gB1 = Bt + (size_t)(n0 + r1) * K + q1 * 8;
    u16* lA0 = &As[0][0] + t * 8;           // elements: *2B = t*16 bytes
    u16* lA1 = &As[0][0] + (t + 256) * 8;
    u16* lB0 = &Bs[0][0] + t * 8;
    u16* lB1 = &Bs[0][0] + (t + 256) * 8;

    for (int k0 = 0; k0 < K; k0 += 32) {
        __syncthreads();                    // prior ds_reads done before overwrite
        async_cp16(gA0 + k0, lA0);
        async_cp16(gA1 + k0, lA1);
        async_cp16(gB0 + k0, lB0);
        async_cp16(gB1 + k0, lB1);
        __syncthreads();                    // vmcnt(0) drain + barrier
        short8 af[4], bfr[4];
#pragma unroll
        for (int i = 0; i < 4; i++) {
            af[i] = *(const short8*)&As[wm + i * 16 + lrow][lq * 8];
            bfr[i] = *(const short8*)&Bs[wn + i * 16 + lrow][lq * 8];
        }
#pragma unroll
        for (int i = 0; i < 4; i++)
#pragma unroll
            for (int j = 0; j < 4; j++)
                acc[i][j] = __builtin_amdgcn_mfma_f32_16x16x32_bf16(af[i], bfr[j], acc[i][j], 0, 0, 0);
    }
    // C/D layout: col = lane&15, row = (lane>>4)*4 + reg
#pragma unroll
    for (int i = 0; i < 4; i++) {
#pragma unroll
        for (int reg = 0; reg < 4; reg++) {
            int gm = m0 + wm + i * 16 + lq * 4 + reg;
            if (gm < M) {
#pragma unroll
                for (int j = 0; j < 4; j++) {
                    int gn = n0 + wn + j * 16 + lrow;
                    C[(size_t)gm * Ntot + gn] = f2bf(acc[i][j][reg]);
                }
            }
        }
    }
}

// ------------------------------------------------- attention score pre-dots
__global__ __launch_bounds__(256) void sdot_wave(const u16* __restrict__ xp,
                                                 const float* __restrict__ a_src,
                                                 const float* __restrict__ a_dst,
                                                 float* __restrict__ s_src,
                                                 float* __restrict__ s_dst) {
    int wave = threadIdx.x >> 6, lane = threadIdx.x & 63;
    int n = blockIdx.x * 4 + wave;
    int col = lane << 2;
    ushort4 v = *(const ushort4*)&xp[(size_t)n * H + col];
    float4 a1 = *(const float4*)&a_src[col];
    float4 a2 = *(const float4*)&a_dst[col];
    float x0 = bf2f(v.x), x1 = bf2f(v.y), x2 = bf2f(v.z), x3 = bf2f(v.w);
    float d1 = x0 * a1.x + x1 * a1.y + x2 * a1.z + x3 * a1.w;
    float d2 = x0 * a2.x + x1 * a2.y + x2 * a2.z + x3 * a2.w;
#pragma unroll
    for (int off = 32; off; off >>= 1) {
        d1 += __shfl_xor(d1, off);
        d2 += __shfl_xor(d2, off);
    }
    if (lane == 0) { s_src[n] = d1; s_dst[n] = d2; }
}

// --------------------------------------------------------- GAT aggregation
// wave per node; (src,w) staged in LDS, gather 8-deep pipelined
__global__ __launch_bounds__(256) void gat_agg_wave(const u16* __restrict__ xp,
                                                    const float* __restrict__ s_src,
                                                    const float* __restrict__ s_dst,
                                                    const int* __restrict__ indptr,
                                                    const int* __restrict__ eids,
                                                    const int* __restrict__ src_arr,
                                                    const float* __restrict__ bias,
                                                    u16* __restrict__ out) {
    __shared__ int   sS[4][64];
    __shared__ float sW[4][64];
    int wave = threadIdx.x >> 6, lane = threadIdx.x & 63;
    int n = blockIdx.x * 4 + wave;
    int start = indptr[n];
    int deg = indptr[n + 1] - start;
    float sdn = s_dst[n];
    int col = lane << 2;
    float a0 = 0.f, a1 = 0.f, a2 = 0.f, a3 = 0.f;

    if (deg <= 64) {
        int s = 0;
        float v = -1e30f;
        if (lane < deg) {
            int e = eids[start + lane];
            s = (e < N_EDGES) ? src_arr[e] : (e - N_EDGES);
            float u = s_src[s] + sdn;
            v = (u >= 0.f) ? u : NEG_SLOPE * u;
        }
        float m = v;
#pragma unroll
        for (int off = 32; off; off >>= 1) m = fmaxf(m, __shfl_xor(m, off));
        float pw = (lane < deg) ? expf(v - m) : 0.f;
        float dsum = pw;
#pragma unroll
        for (int off = 32; off; off >>= 1) dsum += __shfl_xor(dsum, off);
        sS[wave][lane] = s;
        sW[wave][lane] = pw * (1.f / dsum);
        int j = 0;
        for (; j + 8 <= deg; j += 8) {
            ushort4 rv[8];
            float wv[8];
#pragma unroll
            for (int k = 0; k < 8; k++) {
                int sj = sS[wave][j + k];
                wv[k] = sW[wave][j + k];
                rv[k] = *(const ushort4*)&xp[(size_t)sj * H + col];
            }
#pragma unroll
            for (int k = 0; k < 8; k++) {
                a0 += wv[k] * bf2f(rv[k].x);
                a1 += wv[k] * bf2f(rv[k].y);
                a2 += wv[k] * bf2f(rv[k].z);
                a3 += wv[k] * bf2f(rv[k].w);
            }
        }
        if (j + 4 <= deg) {
            ushort4 rv[4];
            float wv[4];
#pragma unroll
            for (int k = 0; k < 4; k++) {
                int sj = sS[wave][j + k];
                wv[k] = sW[wave][j + k];
                rv[k] = *(const ushort4*)&xp[(size_t)sj * H + col];
            }
#pragma unroll
            for (int k = 0; k < 4; k++) {
                a0 += wv[k] * bf2f(rv[k].x);
                a1 += wv[k] * bf2f(rv[k].y);
                a2 += wv[k] * bf2f(rv[k].z);
                a3 += wv[k] * bf2f(rv[k].w);
            }
            j += 4;
        }
        for (; j < deg; j++) {
            int sj = sS[wave][j];
            float wj = sW[wave][j];
            ushort4 rv = *(const ushort4*)&xp[(size_t)sj * H + col];
            a0 += wj * bf2f(rv.x);
            a1 += wj * bf2f(rv.y);
            a2 += wj * bf2f(rv.z);
            a3 += wj * bf2f(rv.w);
        }
    } else {
        // general path (deg>64: essentially never with this graph)
        float m = -1e30f;
        for (int i = lane; i < deg; i += 64) {
            int e = eids[start + i];
            int s = (e < N_EDGES) ? src_arr[e] : (e - N_EDGES);
            float u = s_src[s] + sdn;
            u = (u >= 0.f) ? u : NEG_SLOPE * u;
            m = fmaxf(m, u);
        }
#pragma unroll
        for (int off = 32; off; off >>= 1) m = fmaxf(m, __shfl_xor(m, off));
        float dsum = 0.f;
        for (int i = lane; i < deg; i += 64) {
            int e = eids[start + i];
            int s = (e < N_EDGES) ? src_arr[e] : (e - N_EDGES);
            float u = s_src[s] + sdn;
            u = (u >= 0.f) ? u : NEG_SLOPE * u;
            dsum += expf(u - m);
        }
#pragma unroll
        for (int off = 32; off; off >>= 1) dsum += __shfl_xor(dsum, off);
        float dinv = 1.f / dsum;
        for (int base = 0; base < deg; base += 64) {
            int cnt = min(64, deg - base);
            int s = 0; float w = 0.f;
            if (lane < cnt) {
                int e = eids[start + base + lane];
                s = (e < N_EDGES) ? src_arr[e] : (e - N_EDGES);
                float u = s_src[s] + sdn;
                u = (u >= 0.f) ? u : NEG_SLOPE * u;
                w = expf(u - m) * dinv;
            }
            sS[wave][lane] = s;
            sW[wave][lane] = w;
            for (int j = 0; j < cnt; j++) {
                int sj = sS[wave][j];
                float wj = sW[wave][j];
                ushort4 rv = *(const ushort4*)&xp[(size_t)sj * H + col];
                a0 += wj * bf2f(rv.x);
                a1 += wj * bf2f(rv.y);
                a2 += wj * bf2f(rv.z);
                a3 += wj * bf2f(rv.w);
            }
        }
    }
    float4 bv = *(const float4*)&bias[col];
    ushort4 o;
    o.x = f2bf(fmaxf(a0 + bv.x, 0.f));
    o.y = f2bf(fmaxf(a1 + bv.y, 0.f));
    o.z = f2bf(fmaxf(a2 + bv.z, 0.f));
    o.w = f2bf(fmaxf(a3 + bv.w, 0.f));
    *(ushort4*)&out[(size_t)n * H + col] = o;
}

// ------------------------------------------------- GRU gates + pooling (fused)
__global__ __launch_bounds__(256) void gru_gates_pool(const u16* __restrict__ gates,
                                                      const float* __restrict__ b_ih,
                                                      const float* __restrict__ b_hh,
                                                      const int* __restrict__ batch,
                                                      float* __restrict__ pooled,
                                                      int nodeBase, int nodeCount) {
    int t = threadIdx.x;
    int i0 = blockIdx.x * 16;
    if (i0 >= nodeCount) return;
    float bir = b_ih[t], biz = b_ih[256 + t], bin_ = b_ih[512 + t];
    float bhr = b_hh[t], bhz = b_hh[256 + t], bhn = b_hh[512 + t];
    int iend = min(16, nodeCount - i0);
    float acc = 0.f;
    int cur_g = batch[nodeBase + i0];
    for (int i = 0; i < iend; i++) {
        size_t row = (size_t)(i0 + i) * 768;
        float ir = bf2f(gates[row + t]);
        float iz = bf2f(gates[row + 256 + t]);
        float in_ = bf2f(gates[row + 512 + t]);
        float r = 1.f / (1.f + expf(-(ir + bir + bhr)));
        float z = 1.f / (1.f + expf(-(iz + biz + bhz)));
        float nn = tanhf(in_ + bin_ + r * bhn);
        float h = (1.f - z) * nn;
        int g = batch[nodeBase + i0 + i];
        if (g != cur_g) {
            atomicAdd(&pooled[(size_t)cur_g * H + t], acc);
            acc = 0.f;
            cur_g = g;
        }
        acc += h;
    }
    atomicAdd(&pooled[(size_t)cur_g * H + t], acc);
}

// --------------------------------------------------------------- super node
__global__ __launch_bounds__(256) void super_kernel(const float* __restrict__ pooled,
                                                    const float* __restrict__ Wf,
                                                    const float* __restrict__ bf,
                                                    float* __restrict__ sup) {
    __shared__ float smean[256];
    int t = threadIdx.x;
    float s = 0.f;
    for (int g = 0; g < G_GRAPHS; g++) s += pooled[(size_t)g * H + t];
    smean[t] = s / (float)G_GRAPHS;
    __syncthreads();
    float acc = 0.f;
    for (int k = 0; k < H; k++) acc += smean[k] * Wf[(size_t)t * H + k];
    acc += bf[t];
    sup[t] = fmaxf(acc, 0.f);
}

__global__ __launch_bounds__(256) void writeout(const float* __restrict__ pooled,
                                                const float* __restrict__ sup,
                                                float* __restrict__ out) {
    int idx = blockIdx.x * 256 + threadIdx.x;   // G*2H = 65536
    int g = idx >> 9, c = idx & 511;
    out[idx] = (c < H) ? pooled[(size_t)g * H + c] : sup[c - H];
}

// ---------------------------------------------------------------- launcher
extern "C" void kernel_launch(void* const* d_in, const int* in_sizes, int n_in,
                              void* d_out, int out_size, void* d_ws, size_t ws_size,
                              hipStream_t stream) {
    const float* x      = (const float*)d_in[0];
    const int*   ei     = (const int*)d_in[1];
    const int*   batch  = (const int*)d_in[2];
    const float* W0     = (const float*)d_in[3];
    const float* a_src0 = (const float*)d_in[4];
    const float* a_dst0 = (const float*)d_in[5];
    const float* b0     = (const float*)d_in[6];
    const float* W1     = (const float*)d_in[7];
    const float* a_src1 = (const float*)d_in[8];
    const float* a_dst1 = (const float*)d_in[9];
    const float* b1     = (const float*)d_in[10];
    const float* W_ih   = (const float*)d_in[11];
    // d_in[12] = W_hh unused (h0 = 0)
    const float* b_ih   = (const float*)d_in[13];
    const float* b_hh   = (const float*)d_in[14];
    const float* Wf     = (const float*)d_in[15];
    const float* bf     = (const float*)d_in[16];
    float* out = (float*)d_out;

    char* p = (char*)d_ws;
    auto alloc = [&](size_t bytes) -> void* {
        void* r = (void*)p;
        p += (bytes + 255) & ~(size_t)255;
        return r;
    };
    u16*   xp_bf  = (u16*)alloc((size_t)N_PAD * H * 2);
    u16*   h_bf   = (u16*)alloc((size_t)N_PAD * H * 2);
    u16*   x_bf   = (u16*)alloc((size_t)N_PAD * IN_CH * 2);
    u16*   gatesC = (u16*)alloc((size_t)GRU_CHUNK * 3 * H * 2);
    u16*   W0t    = (u16*)alloc((size_t)H * IN_CH * 2);
    u16*   W1t    = (u16*)alloc((size_t)H * H * 2);
    u16*   Wih_bf = (u16*)alloc((size_t)3 * H * H * 2);
    float* s_src  = (float*)alloc((size_t)N_NODES * 4);
    float* s_dst  = (float*)alloc((size_t)N_NODES * 4);
    int*   counts = (int*)alloc((size_t)N_NODES * 4);
    int*   incl   = (int*)alloc((size_t)N_NODES * 4);
    int*   indptr = (int*)alloc((size_t)(N_NODES + 1) * 4);
    int*   cursor = (int*)alloc((size_t)N_NODES * 4);
    int*   eids   = (int*)alloc((size_t)ET * 4);
    int*   bSums  = (int*)alloc(256 * 4);
    int*   bOff   = (int*)alloc(256 * 4);
    float* pooled = (float*)alloc((size_t)G_GRAPHS * H * 4);
    float* sup    = (float*)alloc((size_t)H * 4);

    const int SB = (N_NODES + 255) / 256;            // 196
    // CSR build (counts zeroed by memset; scan adds the +1 self loop)
    hipMemsetAsync(counts, 0, (size_t)N_NODES * 4, stream);
    hist_kernel<<<(N_EDGES + 255) / 256, 256, 0, stream>>>(ei, counts);
    scan_block<<<SB, 256, 0, stream>>>(counts, incl, bSums);
    scan_sums<<<1, 256, 0, stream>>>(bSums, bOff, SB);
    scan_finalize<<<SB, 256, 0, stream>>>(incl, bOff, indptr, cursor);
    scatter_kernel<<<(ET + 255) / 256, 256, 0, stream>>>(ei, cursor, eids);

    // conversions (single kernel, 4 segments)
    prep_kernel<<<dim3((N_NODES * IN_CH / 4 + 255) / 256, 4), 256, 0, stream>>>(
        x, W_ih, W0, W1, x_bf, Wih_bf, W0t, W1t);

    const int MB = (N_NODES + 127) / 128;            // 391
    const int WB = N_NODES / 4;                      // 12500
    // GAT layer 0
    gemm_mfma<<<dim3(MB, H / 128), 256, 0, stream>>>(x_bf, W0t, xp_bf, N_NODES, IN_CH, H);
    sdot_wave<<<WB, 256, 0, stream>>>(xp_bf, a_src0, a_dst0, s_src, s_dst);
    gat_agg_wave<<<WB, 256, 0, stream>>>(xp_bf, s_src, s_dst, indptr, eids, ei, b0, h_bf);
    // GAT layer 1
    gemm_mfma<<<dim3(MB, H / 128), 256, 0, stream>>>(h_bf, W1t, xp_bf, N_NODES, H, H);
    sdot_wave<<<WB, 256, 0, stream>>>(xp_bf, a_src1, a_dst1, s_src, s_dst);
    gat_agg_wave<<<WB, 256, 0, stream>>>(xp_bf, s_src, s_dst, indptr, eids, ei, b1, h_bf);
    // GRU (chunked) + fused pooling
    hipMemsetAsync(pooled, 0, (size_t)G_GRAPHS * H * 4, stream);
    for (int base = 0; base < N_NODES; base += GRU_CHUNK) {
        int cnt = min(GRU_CHUNK, N_NODES - base);
        gemm_mfma<<<dim3((cnt + 127) / 128, (3 * H) / 128), 256, 0, stream>>>(
            h_bf + (size_t)base * H, Wih_bf, gatesC, cnt, H, 3 * H);
        gru_gates_pool<<<(cnt + 15) / 16, 256, 0, stream>>>(gatesC, b_ih, b_hh, batch, pooled, base, cnt);
    }
    // super node + writeout
    super_kernel<<<1, 256, 0, stream>>>(pooled, Wf, bf, sup);
    writeout<<<(G_GRAPHS * 2 * H) / 256, 256, 0, stream>>>(pooled, sup, out);
}

// Round 5
// 455.850 us; speedup vs baseline: 2.6800x; 1.0712x over previous
//
#include <hip/hip_runtime.h>
#include <hip/hip_fp16.h>
#include <math.h>

#define N_NODES 50000
#define N_PAD   50176            // 392*128, padded rows for unguarded GEMM A-tiles
#define N_EDGES 800000
#define ET (N_EDGES + N_NODES)   // 850000 with self loops
#define IN_CH 128
#define H 256
#define G_GRAPHS 128
#define NEG_SLOPE 0.2f
#define GRU_CHUNK 25000

typedef __attribute__((ext_vector_type(8))) short short8;
typedef __attribute__((ext_vector_type(4))) float f32x4;
typedef unsigned short u16;
typedef unsigned char u8;

#if __has_builtin(__builtin_amdgcn_cvt_f32_fp8) && __has_builtin(__builtin_amdgcn_cvt_pk_fp8_f32)
#define USE_FP8_BUILTINS 1
#else
#define USE_FP8_BUILTINS 0
#endif

__device__ inline u16 f2bf(float v) {
    unsigned u = __float_as_uint(v);
    unsigned r = (u + 0x7FFFu + ((u >> 16) & 1u)) >> 16;
    return (u16)r;
}
__device__ inline float bf2f(u16 v) {
    return __uint_as_float(((unsigned)v) << 16);
}

// ---- fp8 e4m3fn helpers -------------------------------------------------
#if USE_FP8_BUILTINS
#define FP8_WSCALE 1.0f
__device__ inline unsigned fp8_pack4(float a, float b, float c, float d) {
    int v = 0;
    v = __builtin_amdgcn_cvt_pk_fp8_f32(a, b, v, false);
    v = __builtin_amdgcn_cvt_pk_fp8_f32(c, d, v, true);
    return (unsigned)v;
}
// decode 4 fp8 from a packed word
__device__ inline void fp8_dec4(unsigned rv, float& f0, float& f1, float& f2, float& f3) {
    f0 = __builtin_amdgcn_cvt_f32_fp8((int)rv, 0);
    f1 = __builtin_amdgcn_cvt_f32_fp8((int)rv, 1);
    f2 = __builtin_amdgcn_cvt_f32_fp8((int)rv, 2);
    f3 = __builtin_amdgcn_cvt_f32_fp8((int)rv, 3);
}
#else
// fallback: decoded values come out scaled by 2^-8; fold *256 into weights
#define FP8_WSCALE 256.0f
__device__ inline u8 fp8_enc1(float f) {
    unsigned u = __float_as_uint(f);
    unsigned s = (u >> 31) << 7;
    float a = fabsf(f);
    if (a >= 448.f) return (u8)(s | 0x7E);
    unsigned bits = __float_as_uint(a);
    int exp = (int)((bits >> 23) & 255) - 127;
    unsigned m23 = bits & 0x7fffff;
    if (exp < -6) {
        int m = (int)rintf(a * 512.f);
        if (m >= 8) return (u8)(s | (1 << 3));
        return (u8)(s | m);
    }
    int e8 = exp + 7;
    unsigned m = m23 >> 20, rem = m23 & 0xFFFFF;
    if (rem > 0x80000 || (rem == 0x80000 && (m & 1))) m++;
    if (m == 8) { m = 0; e8++; }
    if (e8 > 15 || (e8 == 15 && m == 7)) return (u8)(s | 0x7E);
    return (u8)(s | (e8 << 3) | m);
}
__device__ inline unsigned fp8_pack4(float a, float b, float c, float d) {
    return (unsigned)fp8_enc1(a) | ((unsigned)fp8_enc1(b) << 8) |
           ((unsigned)fp8_enc1(c) << 16) | ((unsigned)fp8_enc1(d) << 24);
}
// half-trick decode: e4m3 bits placed into f16 gives value * 2^-8
// (fp8 subnormals flush to ~0: |err| < 0.014, negligible for features)
__device__ inline void fp8_dec4(unsigned rv, float& f0, float& f1, float& f2, float& f3) {
    unsigned hA = ((rv & 0x00800080u) << 8) | ((rv & 0x007f007fu) << 7);   // bytes 0,2
    unsigned rs = rv >> 8;
    unsigned hB = ((rs & 0x00800080u) << 8) | ((rs & 0x007f007fu) << 7);   // bytes 1,3
    __half2 a = *(__half2*)&hA;
    __half2 b = *(__half2*)&hB;
    f0 = __low2float(a);  f2 = __high2float(a);
    f1 = __low2float(b);  f3 = __high2float(b);
}
#endif

// async global->LDS 16B copy (dest must be wave-uniform base + lane*16)
__device__ inline void async_cp16(const u16* g, u16* l) {
    __builtin_amdgcn_global_load_lds(
        (const __attribute__((address_space(1))) unsigned int*)g,
        (__attribute__((address_space(3))) unsigned int*)l,
        16, 0, 0);
}

// ---------------------------------------------------------------- CSR build
__global__ __launch_bounds__(256) void hist_kernel(const int* __restrict__ ei,
                                                   int* __restrict__ counts) {
    int e = blockIdx.x * 256 + threadIdx.x;
    if (e < N_EDGES) atomicAdd(&counts[ei[N_EDGES + e]], 1);
}

// scan over (counts[i] + 1)  — the +1 is the self loop
__global__ __launch_bounds__(256) void scan_block(const int* __restrict__ in,
                                                  int* __restrict__ incl,
                                                  int* __restrict__ blockSums) {
    __shared__ int s[256];
    int t = threadIdx.x;
    int i = blockIdx.x * 256 + t;
    int v = (i < N_NODES) ? (in[i] + 1) : 0;
    s[t] = v;
    __syncthreads();
    for (int off = 1; off < 256; off <<= 1) {
        int x = 0;
        if (t >= off) x = s[t - off];
        __syncthreads();
        if (t >= off) s[t] += x;
        __syncthreads();
    }
    if (i < N_NODES) incl[i] = s[t];
    if (t == 255) blockSums[blockIdx.x] = s[255];
}

__global__ __launch_bounds__(256) void scan_sums(const int* __restrict__ blockSums,
                                                 int* __restrict__ blockOff, int nb) {
    __shared__ int s[256];
    int t = threadIdx.x;
    int v = (t < nb) ? blockSums[t] : 0;
    s[t] = v;
    __syncthreads();
    for (int off = 1; off < 256; off <<= 1) {
        int x = 0;
        if (t >= off) x = s[t - off];
        __syncthreads();
        if (t >= off) s[t] += x;
        __syncthreads();
    }
    if (t < nb) blockOff[t] = s[t] - v;   // exclusive
}

__global__ __launch_bounds__(256) void scan_finalize(const int* __restrict__ incl,
                                                     const int* __restrict__ blockOff,
                                                     int* __restrict__ indptr,
                                                     int* __restrict__ cursor) {
    int i = blockIdx.x * 256 + threadIdx.x;
    if (i < N_NODES) {
        int v = incl[i] + blockOff[i >> 8];
        indptr[i + 1] = v;
        if (i + 1 < N_NODES) cursor[i + 1] = v;
    }
    if (i == 0) { indptr[0] = 0; cursor[0] = 0; }
}

__global__ __launch_bounds__(256) void scatter_kernel(const int* __restrict__ ei,
                                                      int* __restrict__ cursor,
                                                      int* __restrict__ eids) {
    int e = blockIdx.x * 256 + threadIdx.x;
    if (e < ET) {
        int dst = (e < N_EDGES) ? ei[N_EDGES + e] : (e - N_EDGES);
        int pos = atomicAdd(&cursor[dst], 1);
        eids[pos] = e;
    }
}

// ------------------------------------------------- combined conversions
__global__ __launch_bounds__(256) void prep_kernel(const float* __restrict__ x,
                                                   const float* __restrict__ Wih,
                                                   const float* __restrict__ W0,
                                                   const float* __restrict__ W1,
                                                   u16* __restrict__ x_bf,
                                                   u16* __restrict__ Wih_bf,
                                                   u16* __restrict__ W0t,
                                                   u16* __restrict__ W1t) {
    int i = blockIdx.x * 256 + threadIdx.x;
    int seg = blockIdx.y;
    if (seg == 0) {
        if (i < N_NODES * IN_CH / 4) {
            float4 v = *(const float4*)&x[i * 4];
            ushort4 o = {f2bf(v.x), f2bf(v.y), f2bf(v.z), f2bf(v.w)};
            *(ushort4*)&x_bf[i * 4] = o;
        }
    } else if (seg == 1) {
        if (i < 3 * H * H / 4) {
            float4 v = *(const float4*)&Wih[i * 4];
            ushort4 o = {f2bf(v.x), f2bf(v.y), f2bf(v.z), f2bf(v.w)};
            *(ushort4*)&Wih_bf[i * 4] = o;
        }
    } else if (seg == 2) {
        if (i < IN_CH * H) {
            int k = i / H, n = i % H;
            W0t[(size_t)n * IN_CH + k] = f2bf(W0[i]);
        }
    } else {
        if (i < H * H) {
            int k = i / H, n = i % H;
            W1t[(size_t)n * H + k] = f2bf(W1[i]);
        }
    }
}

// ------------------------------------------------------------ MFMA GEMM (wide)
// C[M,Ntot] = A[M,K](bf16) @ Bt[Ntot,K]^T (bf16), fp32 acc, bf16 out.
// 128x256 tile, BK=32, 256 thr = 4 waves (2m x 2n of 64x128).
// global_load_lds staging; A buffers padded to N_PAD rows (unguarded reads).
__global__ __launch_bounds__(256, 2) void gemm_wide(const u16* __restrict__ A,
                                                    const u16* __restrict__ Bt,
                                                    u16* __restrict__ C,
                                                    int M, int K, int Ntot) {
    __shared__ u16 As[128][32];   // 8 KB, NO pad (global_load_lds contiguity)
    __shared__ u16 Bs[256][32];   // 16 KB
    int t = threadIdx.x;
    int m0 = blockIdx.x * 128;
    int n0 = blockIdx.y * 256;
    int wave = t >> 6, lane = t & 63;
    int wm = (wave >> 1) * 64, wn = (wave & 1) * 128;
    int lrow = lane & 15;
    int lq = lane >> 4;

    f32x4 acc[4][8];
#pragma unroll
    for (int i = 0; i < 4; i++)
#pragma unroll
        for (int j = 0; j < 8; j++)
            acc[i][j] = (f32x4){0.f, 0.f, 0.f, 0.f};

    // 16B chunk c of a tile lives at LDS offset c*16; thread t stages
    // chunks {t, t+256(A) | t,t+256,t+512,t+768(B)} -> dest = wave-uniform + lane*16
    int r0 = t >> 2, q0 = t & 3;
    const u16* gA0 = A + (size_t)(m0 + r0) * K + q0 * 8;
    const u16* gA1 = gA0 + (size_t)64 * K;
    const u16* gB0 = Bt + (size_t)(n0 + r0) * K + q0 * 8;
    const u16* gB1 = gB0 + (size_t)64 * K;
    const u16* gB2 = gB0 + (size_t)128 * K;
    const u16* gB3 = gB0 + (size_t)192 * K;
    u16* lA0 = &As[0][0] + t * 8;
    u16* lA1 = lA0 + 256 * 8;
    u16* lB0 = &Bs[0][0] + t * 8;
    u16* lB1 = lB0 + 256 * 8;
    u16* lB2 = lB0 + 512 * 8;
    u16* lB3 = lB0 + 768 * 8;

    for (int k0 = 0; k0 < K; k0 += 32) {
        __syncthreads();
        async_cp16(gA0 + k0, lA0);
        async_cp16(gA1 + k0, lA1);
        async_cp16(gB0 + k0, lB0);
        async_cp16(gB1 + k0, lB1);
        async_cp16(gB2 + k0, lB2);
        async_cp16(gB3 + k0, lB3);
        __syncthreads();
        short8 af[4], bfr[8];
#pragma unroll
        for (int i = 0; i < 4; i++)
            af[i] = *(const short8*)&As[wm + i * 16 + lrow][lq * 8];
#pragma unroll
        for (int j = 0; j < 8; j++)
            bfr[j] = *(const short8*)&Bs[wn + j * 16 + lrow][lq * 8];
#pragma unroll
        for (int i = 0; i < 4; i++)
#pragma unroll
            for (int j = 0; j < 8; j++)
                acc[i][j] = __builtin_amdgcn_mfma_f32_16x16x32_bf16(af[i], bfr[j], acc[i][j], 0, 0, 0);
    }
    // C/D layout: col = lane&15, row = (lane>>4)*4 + reg
#pragma unroll
    for (int i = 0; i < 4; i++) {
#pragma unroll
        for (int reg = 0; reg < 4; reg++) {
            int gm = m0 + wm + i * 16 + lq * 4 + reg;
            if (gm < M) {
#pragma unroll
                for (int j = 0; j < 8; j++) {
                    int gn = n0 + wn + j * 16 + lrow;
                    C[(size_t)gm * Ntot + gn] = f2bf(acc[i][j][reg]);
                }
            }
        }
    }
}

// ------------------------------------------- attention pre-dots + fp8 encode
// wave per node; lane covers 4 cols; also writes fp8 copy of xp
__global__ __launch_bounds__(256) void sdot_fp8(const u16* __restrict__ xp,
                                                const float* __restrict__ a_src,
                                                const float* __restrict__ a_dst,
                                                float* __restrict__ s_src,
                                                float* __restrict__ s_dst,
                                                u8* __restrict__ xp8) {
    int wave = threadIdx.x >> 6, lane = threadIdx.x & 63;
    int n = blockIdx.x * 4 + wave;
    int col = lane << 2;
    ushort4 v = *(const ushort4*)&xp[(size_t)n * H + col];
    float4 a1 = *(const float4*)&a_src[col];
    float4 a2 = *(const float4*)&a_dst[col];
    float x0 = bf2f(v.x), x1 = bf2f(v.y), x2 = bf2f(v.z), x3 = bf2f(v.w);
    *(unsigned*)&xp8[(size_t)n * H + col] = fp8_pack4(x0, x1, x2, x3);
    float d1 = x0 * a1.x + x1 * a1.y + x2 * a1.z + x3 * a1.w;
    float d2 = x0 * a2.x + x1 * a2.y + x2 * a2.z + x3 * a2.w;
#pragma unroll
    for (int off = 32; off; off >>= 1) {
        d1 += __shfl_xor(d1, off);
        d2 += __shfl_xor(d2, off);
    }
    if (lane == 0) { s_src[n] = d1; s_dst[n] = d2; }
}

// --------------------------------------------------------- GAT aggregation
// wave per node; fp8 value gather (4 B/lane, 256 B/row), bf16 out (+bias, relu)
__global__ __launch_bounds__(256) void gat_agg_fp8(const u8* __restrict__ xp8,
                                                   const float* __restrict__ s_src,
                                                   const float* __restrict__ s_dst,
                                                   const int* __restrict__ indptr,
                                                   const int* __restrict__ eids,
                                                   const int* __restrict__ src_arr,
                                                   const float* __restrict__ bias,
                                                   u16* __restrict__ out) {
    __shared__ int   sS[4][64];
    __shared__ float sW[4][64];
    int wave = threadIdx.x >> 6, lane = threadIdx.x & 63;
    int n = blockIdx.x * 4 + wave;
    int start = indptr[n];
    int deg = indptr[n + 1] - start;
    float sdn = s_dst[n];
    int col = lane << 2;
    float a0 = 0.f, a1 = 0.f, a2 = 0.f, a3 = 0.f;

    if (deg <= 64) {
        int s = 0;
        float v = -1e30f;
        if (lane < deg) {
            int e = eids[start + lane];
            s = (e < N_EDGES) ? src_arr[e] : (e - N_EDGES);
            float u = s_src[s] + sdn;
            v = (u >= 0.f) ? u : NEG_SLOPE * u;
        }
        float m = v;
#pragma unroll
        for (int off = 32; off; off >>= 1) m = fmaxf(m, __shfl_xor(m, off));
        float pw = (lane < deg) ? expf(v - m) : 0.f;
        float dsum = pw;
#pragma unroll
        for (int off = 32; off; off >>= 1) dsum += __shfl_xor(dsum, off);
        sS[wave][lane] = s;
        sW[wave][lane] = pw * (FP8_WSCALE / dsum);
        int j = 0;
        for (; j + 8 <= deg; j += 8) {
            unsigned rv[8];
            float wv[8];
#pragma unroll
            for (int k = 0; k < 8; k++) {
                int sj = sS[wave][j + k];
                wv[k] = sW[wave][j + k];
                rv[k] = *(const unsigned*)&xp8[(size_t)sj * H + col];
            }
#pragma unroll
            for (int k = 0; k < 8; k++) {
                float f0, f1, f2, f3;
                fp8_dec4(rv[k], f0, f1, f2, f3);
                a0 += wv[k] * f0; a1 += wv[k] * f1;
                a2 += wv[k] * f2; a3 += wv[k] * f3;
            }
        }
        for (; j < deg; j++) {
            int sj = sS[wave][j];
            float wj = sW[wave][j];
            unsigned rv = *(const unsigned*)&xp8[(size_t)sj * H + col];
            float f0, f1, f2, f3;
            fp8_dec4(rv, f0, f1, f2, f3);
            a0 += wj * f0; a1 += wj * f1; a2 += wj * f2; a3 += wj * f3;
        }
    } else {
        // general path (deg>64: essentially never with this graph)
        float m = -1e30f;
        for (int i = lane; i < deg; i += 64) {
            int e = eids[start + i];
            int s = (e < N_EDGES) ? src_arr[e] : (e - N_EDGES);
            float u = s_src[s] + sdn;
            u = (u >= 0.f) ? u : NEG_SLOPE * u;
            m = fmaxf(m, u);
        }
#pragma unroll
        for (int off = 32; off; off >>= 1) m = fmaxf(m, __shfl_xor(m, off));
        float dsum = 0.f;
        for (int i = lane; i < deg; i += 64) {
            int e = eids[start + i];
            int s = (e < N_EDGES) ? src_arr[e] : (e - N_EDGES);
            float u = s_src[s] + sdn;
            u = (u >= 0.f) ? u : NEG_SLOPE * u;
            dsum += expf(u - m);
        }
#pragma unroll
        for (int off = 32; off; off >>= 1) dsum += __shfl_xor(dsum, off);
        float dinv = FP8_WSCALE / dsum;
        for (int base = 0; base < deg; base += 64) {
            int cnt = min(64, deg - base);
            int s = 0; float w = 0.f;
            if (lane < cnt) {
                int e = eids[start + base + lane];
                s = (e < N_EDGES) ? src_arr[e] : (e - N_EDGES);
                float u = s_src[s] + sdn;
                u = (u >= 0.f) ? u : NEG_SLOPE * u;
                w = expf(u - m) * dinv;
            }
            sS[wave][lane] = s;
            sW[wave][lane] = w;
            for (int j = 0; j < cnt; j++) {
                int sj = sS[wave][j];
                float wj = sW[wave][j];
                unsigned rv = *(const unsigned*)&xp8[(size_t)sj * H + col];
                float f0, f1, f2, f3;
                fp8_dec4(rv, f0, f1, f2, f3);
                a0 += wj * f0; a1 += wj * f1; a2 += wj * f2; a3 += wj * f3;
            }
        }
    }
    float4 bv = *(const float4*)&bias[col];
    ushort4 o;
    o.x = f2bf(fmaxf(a0 + bv.x, 0.f));
    o.y = f2bf(fmaxf(a1 + bv.y, 0.f));
    o.z = f2bf(fmaxf(a2 + bv.z, 0.f));
    o.w = f2bf(fmaxf(a3 + bv.w, 0.f));
    *(ushort4*)&out[(size_t)n * H + col] = o;
}

// ------------------------------------------------- GRU gates + pooling (fused)
__global__ __launch_bounds__(256) void gru_gates_pool(const u16* __restrict__ gates,
                                                      const float* __restrict__ b_ih,
                                                      const float* __restrict__ b_hh,
                                                      const int* __restrict__ batch,
                                                      float* __restrict__ pooled,
                                                      int nodeBase, int nodeCount) {
    int t = threadIdx.x;
    int i0 = blockIdx.x * 16;
    if (i0 >= nodeCount) return;
    float bir = b_ih[t], biz = b_ih[256 + t], bin_ = b_ih[512 + t];
    float bhr = b_hh[t], bhz = b_hh[256 + t], bhn = b_hh[512 + t];
    int iend = min(16, nodeCount - i0);
    float acc = 0.f;
    int cur_g = batch[nodeBase + i0];
    for (int i = 0; i < iend; i++) {
        size_t row = (size_t)(i0 + i) * 768;
        float ir = bf2f(gates[row + t]);
        float iz = bf2f(gates[row + 256 + t]);
        float in_ = bf2f(gates[row + 512 + t]);
        float r = 1.f / (1.f + expf(-(ir + bir + bhr)));
        float z = 1.f / (1.f + expf(-(iz + biz + bhz)));
        float nn = tanhf(in_ + bin_ + r * bhn);
        float h = (1.f - z) * nn;
        int g = batch[nodeBase + i0 + i];
        if (g != cur_g) {
            atomicAdd(&pooled[(size_t)cur_g * H + t], acc);
            acc = 0.f;
            cur_g = g;
        }
        acc += h;
    }
    atomicAdd(&pooled[(size_t)cur_g * H + t], acc);
}

// --------------------------------------------------------------- super node
__global__ __launch_bounds__(256) void super_kernel(const float* __restrict__ pooled,
                                                    const float* __restrict__ Wf,
                                                    const float* __restrict__ bf,
                                                    float* __restrict__ sup) {
    __shared__ float smean[256];
    int t = threadIdx.x;
    float s = 0.f;
    for (int g = 0; g < G_GRAPHS; g++) s += pooled[(size_t)g * H + t];
    smean[t] = s / (float)G_GRAPHS;
    __syncthreads();
    float acc = 0.f;
    for (int k = 0; k < H; k++) acc += smean[k] * Wf[(size_t)t * H + k];
    acc += bf[t];
    sup[t] = fmaxf(acc, 0.f);
}

__global__ __launch_bounds__(256) void writeout(const float* __restrict__ pooled,
                                                const float* __restrict__ sup,
                                                float* __restrict__ out) {
    int idx = blockIdx.x * 256 + threadIdx.x;   // G*2H = 65536
    int g = idx >> 9, c = idx & 511;
    out[idx] = (c < H) ? pooled[(size_t)g * H + c] : sup[c - H];
}

// ---------------------------------------------------------------- launcher
extern "C" void kernel_launch(void* const* d_in, const int* in_sizes, int n_in,
                              void* d_out, int out_size, void* d_ws, size_t ws_size,
                              hipStream_t stream) {
    const float* x      = (const float*)d_in[0];
    const int*   ei     = (const int*)d_in[1];
    const int*   batch  = (const int*)d_in[2];
    const float* W0     = (const float*)d_in[3];
    const float* a_src0 = (const float*)d_in[4];
    const float* a_dst0 = (const float*)d_in[5];
    const float* b0     = (const float*)d_in[6];
    const float* W1     = (const float*)d_in[7];
    const float* a_src1 = (const float*)d_in[8];
    const float* a_dst1 = (const float*)d_in[9];
    const float* b1     = (const float*)d_in[10];
    const float* W_ih   = (const float*)d_in[11];
    // d_in[12] = W_hh unused (h0 = 0)
    const float* b_ih   = (const float*)d_in[13];
    const float* b_hh   = (const float*)d_in[14];
    const float* Wf     = (const float*)d_in[15];
    const float* bf     = (const float*)d_in[16];
    float* out = (float*)d_out;

    char* p = (char*)d_ws;
    auto alloc = [&](size_t bytes) -> void* {
        void* r = (void*)p;
        p += (bytes + 255) & ~(size_t)255;
        return r;
    };
    u16*   xp_bf  = (u16*)alloc((size_t)N_PAD * H * 2);
    u16*   h_bf   = (u16*)alloc((size_t)N_PAD * H * 2);
    u16*   x_bf   = (u16*)alloc((size_t)N_PAD * IN_CH * 2);   // dead after gemm L0
    u8*    xp8    = (u8*)x_bf;                                 // alias: N_PAD*H*1 == N_PAD*IN_CH*2
    u16*   gatesC = (u16*)alloc((size_t)GRU_CHUNK * 3 * H * 2);
    u16*   W0t    = (u16*)alloc((size_t)H * IN_CH * 2);
    u16*   W1t    = (u16*)alloc((size_t)H * H * 2);
    u16*   Wih_bf = (u16*)alloc((size_t)3 * H * H * 2);
    float* s_src  = (float*)alloc((size_t)N_NODES * 4);
    float* s_dst  = (float*)alloc((size_t)N_NODES * 4);
    int*   counts = (int*)alloc((size_t)N_NODES * 4);
    int*   incl   = (int*)alloc((size_t)N_NODES * 4);
    int*   indptr = (int*)alloc((size_t)(N_NODES + 1) * 4);
    int*   cursor = (int*)alloc((size_t)N_NODES * 4);
    int*   eids   = (int*)alloc((size_t)ET * 4);
    int*   bSums  = (int*)alloc(256 * 4);
    int*   bOff   = (int*)alloc(256 * 4);
    float* pooled = (float*)alloc((size_t)G_GRAPHS * H * 4);
    float* sup    = (float*)alloc((size_t)H * 4);

    const int SB = (N_NODES + 255) / 256;            // 196
    // CSR build
    hipMemsetAsync(counts, 0, (size_t)N_NODES * 4, stream);
    hist_kernel<<<(N_EDGES + 255) / 256, 256, 0, stream>>>(ei, counts);
    scan_block<<<SB, 256, 0, stream>>>(counts, incl, bSums);
    scan_sums<<<1, 256, 0, stream>>>(bSums, bOff, SB);
    scan_finalize<<<SB, 256, 0, stream>>>(incl, bOff, indptr, cursor);
    scatter_kernel<<<(ET + 255) / 256, 256, 0, stream>>>(ei, cursor, eids);

    // conversions
    prep_kernel<<<dim3((N_NODES * IN_CH / 4 + 255) / 256, 4), 256, 0, stream>>>(
        x, W_ih, W0, W1, x_bf, Wih_bf, W0t, W1t);

    const int MB = (N_NODES + 127) / 128;            // 391
    const int WB = N_NODES / 4;                      // 12500
    // GAT layer 0 (Ntot=256 -> single y tile)
    gemm_wide<<<dim3(MB, 1), 256, 0, stream>>>(x_bf, W0t, xp_bf, N_NODES, IN_CH, H);
    sdot_fp8<<<WB, 256, 0, stream>>>(xp_bf, a_src0, a_dst0, s_src, s_dst, xp8);
    gat_agg_fp8<<<WB, 256, 0, stream>>>(xp8, s_src, s_dst, indptr, eids, ei, b0, h_bf);
    // GAT layer 1
    gemm_wide<<<dim3(MB, 1), 256, 0, stream>>>(h_bf, W1t, xp_bf, N_NODES, H, H);
    sdot_fp8<<<WB, 256, 0, stream>>>(xp_bf, a_src1, a_dst1, s_src, s_dst, xp8);
    gat_agg_fp8<<<WB, 256, 0, stream>>>(xp8, s_src, s_dst, indptr, eids, ei, b1, h_bf);
    // GRU (chunked) + fused pooling
    hipMemsetAsync(pooled, 0, (size_t)G_GRAPHS * H * 4, stream);
    for (int base = 0; base < N_NODES; base += GRU_CHUNK) {
        int cnt = min(GRU_CHUNK, N_NODES - base);
        gemm_wide<<<dim3((cnt + 127) / 128, 3), 256, 0, stream>>>(
            h_bf + (size_t)base * H, Wih_bf, gatesC, cnt, H, 3 * H);
        gru_gates_pool<<<(cnt + 15) / 16, 256, 0, stream>>>(gatesC, b_ih, b_hh, batch, pooled, base, cnt);
    }
    // super node + writeout
    super_kernel<<<1, 256, 0, stream>>>(pooled, Wf, bf, sup);
    writeout<<<(G_GRAPHS * 2 * H) / 256, 256, 0, stream>>>(pooled, sup, out);
}

// Round 6
// 394.565 us; speedup vs baseline: 3.0963x; 1.1553x over previous
//
#include <hip/hip_runtime.h>
#include <hip/hip_fp16.h>
#include <math.h>

#define N_NODES 50000
#define N_PAD   50176            // 392*128, padded rows for unguarded GEMM A-tiles
#define N_EDGES 800000
#define ET (N_EDGES + N_NODES)   // 850000 with self loops
#define IN_CH 128
#define H 256
#define G_GRAPHS 128
#define NEG_SLOPE 0.2f
#define GRU_CHUNK 25000
#define NB 391                   // node buckets of 128: ceil(50000/128)

typedef __attribute__((ext_vector_type(8))) short short8;
typedef __attribute__((ext_vector_type(4))) float f32x4;
typedef unsigned short u16;
typedef unsigned char u8;

#if __has_builtin(__builtin_amdgcn_cvt_f32_fp8) && __has_builtin(__builtin_amdgcn_cvt_pk_fp8_f32)
#define USE_FP8_BUILTINS 1
#else
#define USE_FP8_BUILTINS 0
#endif

__device__ inline u16 f2bf(float v) {
    unsigned u = __float_as_uint(v);
    unsigned r = (u + 0x7FFFu + ((u >> 16) & 1u)) >> 16;
    return (u16)r;
}
__device__ inline float bf2f(u16 v) {
    return __uint_as_float(((unsigned)v) << 16);
}

// ---- fp8 e4m3fn helpers -------------------------------------------------
#if USE_FP8_BUILTINS
#define FP8_WSCALE 1.0f
__device__ inline unsigned fp8_pack4(float a, float b, float c, float d) {
    int v = 0;
    v = __builtin_amdgcn_cvt_pk_fp8_f32(a, b, v, false);
    v = __builtin_amdgcn_cvt_pk_fp8_f32(c, d, v, true);
    return (unsigned)v;
}
__device__ inline void fp8_dec4(unsigned rv, float& f0, float& f1, float& f2, float& f3) {
    f0 = __builtin_amdgcn_cvt_f32_fp8((int)rv, 0);
    f1 = __builtin_amdgcn_cvt_f32_fp8((int)rv, 1);
    f2 = __builtin_amdgcn_cvt_f32_fp8((int)rv, 2);
    f3 = __builtin_amdgcn_cvt_f32_fp8((int)rv, 3);
}
#else
#define FP8_WSCALE 256.0f
__device__ inline u8 fp8_enc1(float f) {
    unsigned u = __float_as_uint(f);
    unsigned s = (u >> 31) << 7;
    float a = fabsf(f);
    if (a >= 448.f) return (u8)(s | 0x7E);
    unsigned bits = __float_as_uint(a);
    int exp = (int)((bits >> 23) & 255) - 127;
    unsigned m23 = bits & 0x7fffff;
    if (exp < -6) {
        int m = (int)rintf(a * 512.f);
        if (m >= 8) return (u8)(s | (1 << 3));
        return (u8)(s | m);
    }
    int e8 = exp + 7;
    unsigned m = m23 >> 20, rem = m23 & 0xFFFFF;
    if (rem > 0x80000 || (rem == 0x80000 && (m & 1))) m++;
    if (m == 8) { m = 0; e8++; }
    if (e8 > 15 || (e8 == 15 && m == 7)) return (u8)(s | 0x7E);
    return (u8)(s | (e8 << 3) | m);
}
__device__ inline unsigned fp8_pack4(float a, float b, float c, float d) {
    return (unsigned)fp8_enc1(a) | ((unsigned)fp8_enc1(b) << 8) |
           ((unsigned)fp8_enc1(c) << 16) | ((unsigned)fp8_enc1(d) << 24);
}
__device__ inline void fp8_dec4(unsigned rv, float& f0, float& f1, float& f2, float& f3) {
    unsigned hA = ((rv & 0x00800080u) << 8) | ((rv & 0x007f007fu) << 7);
    unsigned rs = rv >> 8;
    unsigned hB = ((rs & 0x00800080u) << 8) | ((rs & 0x007f007fu) << 7);
    __half2 a = *(__half2*)&hA;
    __half2 b = *(__half2*)&hB;
    f0 = __low2float(a);  f2 = __high2float(a);
    f1 = __low2float(b);  f3 = __high2float(b);
}
#endif

// async global->LDS 16B copy (dest must be wave-uniform base + lane*16)
__device__ inline void async_cp16(const u16* g, u16* l) {
    __builtin_amdgcn_global_load_lds(
        (const __attribute__((address_space(1))) unsigned int*)g,
        (__attribute__((address_space(3))) unsigned int*)l,
        16, 0, 0);
}

// =========================== CSR build (bucketed) ========================
// Bucket b covers nodes [b*128, b*128+128). rec[] holds (src,dst) per edge
// grouped by bucket; final pass scatters src into per-node CSR slots.

__global__ __launch_bounds__(256) void bucket_hist(const int* __restrict__ ei,
                                                   int* __restrict__ gcnt) {
    __shared__ int h[NB];
    int t = threadIdx.x;
    for (int b = t; b < NB; b += 256) h[b] = 0;
    __syncthreads();
    for (int e = blockIdx.x * 256 + t; e < N_EDGES; e += gridDim.x * 256)
        atomicAdd(&h[ei[N_EDGES + e] >> 7], 1);
    __syncthreads();
    for (int b = t; b < NB; b += 256)
        if (h[b]) atomicAdd(&gcnt[b], h[b]);
}

__global__ __launch_bounds__(512) void bucket_scan(const int* __restrict__ gcnt,
                                                   int* __restrict__ off,
                                                   int* __restrict__ cur) {
    __shared__ int s[NB + 1];
    int t = threadIdx.x;
    if (t < NB) s[t] = gcnt[t];
    __syncthreads();
    if (t == 0) {
        int a = 0;
        for (int b = 0; b < NB; b++) { int c = s[b]; s[b] = a; a += c; }
        s[NB] = a;
    }
    __syncthreads();
    if (t <= NB) { off[t] = s[t]; if (t < NB) cur[t] = s[t]; }
}

#define EPT 16
__global__ __launch_bounds__(256) void bucket_scatter(const int* __restrict__ ei,
                                                      int* __restrict__ bucketCur,
                                                      int2* __restrict__ rec) {
    __shared__ int cnt[NB];
    __shared__ int base[NB];
    int t = threadIdx.x;
    for (int b = t; b < NB; b += 256) cnt[b] = 0;
    __syncthreads();
    int e0 = blockIdx.x * (256 * EPT);
    int sa[EPT], da[EPT], rk[EPT];
#pragma unroll
    for (int k = 0; k < EPT; k++) {
        int e = e0 + k * 256 + t;
        if (e < N_EDGES) {
            sa[k] = ei[e];
            da[k] = ei[N_EDGES + e];
            rk[k] = atomicAdd(&cnt[da[k] >> 7], 1);
        }
    }
    __syncthreads();
    for (int b = t; b < NB; b += 256) {
        int c = cnt[b];
        base[b] = c ? atomicAdd(&bucketCur[b], c) : 0;
    }
    __syncthreads();
#pragma unroll
    for (int k = 0; k < EPT; k++) {
        int e = e0 + k * 256 + t;
        if (e < N_EDGES) rec[base[da[k] >> 7] + rk[k]] = make_int2(sa[k], da[k]);
    }
}

__global__ __launch_bounds__(256) void node_hist(const int2* __restrict__ rec,
                                                 const int* __restrict__ off,
                                                 int* __restrict__ counts) {
    __shared__ int cnt[128];
    int b = blockIdx.x, t = threadIdx.x;
    if (t < 128) cnt[t] = 1;   // self loop
    __syncthreads();
    int lo = off[b], hi = off[b + 1];
    for (int i = lo + t; i < hi; i += 256) atomicAdd(&cnt[rec[i].y & 127], 1);
    __syncthreads();
    int node = b * 128 + t;
    if (t < 128 && node < N_NODES) counts[node] = cnt[t];
}

__global__ __launch_bounds__(256) void scan_block(const int* __restrict__ in,
                                                  int* __restrict__ incl,
                                                  int* __restrict__ blockSums) {
    __shared__ int s[256];
    int t = threadIdx.x;
    int i = blockIdx.x * 256 + t;
    int v = (i < N_NODES) ? in[i] : 0;
    s[t] = v;
    __syncthreads();
    for (int off = 1; off < 256; off <<= 1) {
        int x = 0;
        if (t >= off) x = s[t - off];
        __syncthreads();
        if (t >= off) s[t] += x;
        __syncthreads();
    }
    if (i < N_NODES) incl[i] = s[t];
    if (t == 255) blockSums[blockIdx.x] = s[255];
}

__global__ __launch_bounds__(256) void scan_sums(const int* __restrict__ blockSums,
                                                 int* __restrict__ blockOff, int nb) {
    __shared__ int s[256];
    int t = threadIdx.x;
    int v = (t < nb) ? blockSums[t] : 0;
    s[t] = v;
    __syncthreads();
    for (int off = 1; off < 256; off <<= 1) {
        int x = 0;
        if (t >= off) x = s[t - off];
        __syncthreads();
        if (t >= off) s[t] += x;
        __syncthreads();
    }
    if (t < nb) blockOff[t] = s[t] - v;   // exclusive
}

__global__ __launch_bounds__(256) void scan_finalize(const int* __restrict__ incl,
                                                     const int* __restrict__ blockOff,
                                                     int* __restrict__ indptr) {
    int i = blockIdx.x * 256 + threadIdx.x;
    if (i < N_NODES) indptr[i + 1] = incl[i] + blockOff[i >> 8];
    if (i == 0) indptr[0] = 0;
}

__global__ __launch_bounds__(256) void final_scatter(const int2* __restrict__ rec,
                                                     const int* __restrict__ off,
                                                     const int* __restrict__ indptr,
                                                     int* __restrict__ eidsSrc) {
    __shared__ int cur[128];
    int b = blockIdx.x, t = threadIdx.x;
    int node = b * 128 + t;
    if (t < 128 && node < N_NODES) {
        int ip = indptr[node];
        eidsSrc[ip] = node;       // self loop slot
        cur[t] = ip + 1;
    }
    __syncthreads();
    int lo = off[b], hi = off[b + 1];
    for (int i = lo + t; i < hi; i += 256) {
        int2 r = rec[i];
        int pos = atomicAdd(&cur[r.y & 127], 1);
        eidsSrc[pos] = r.x;
    }
}

// ------------------------------------------------- combined conversions
__global__ __launch_bounds__(256) void prep_kernel(const float* __restrict__ x,
                                                   const float* __restrict__ Wih,
                                                   const float* __restrict__ W0,
                                                   const float* __restrict__ W1,
                                                   u16* __restrict__ x_bf,
                                                   u16* __restrict__ Wih_bf,
                                                   u16* __restrict__ W0t,
                                                   u16* __restrict__ W1t) {
    int i = blockIdx.x * 256 + threadIdx.x;
    int seg = blockIdx.y;
    if (seg == 0) {
        if (i < N_NODES * IN_CH / 4) {
            float4 v = *(const float4*)&x[i * 4];
            ushort4 o = {f2bf(v.x), f2bf(v.y), f2bf(v.z), f2bf(v.w)};
            *(ushort4*)&x_bf[i * 4] = o;
        }
    } else if (seg == 1) {
        if (i < 3 * H * H / 4) {
            float4 v = *(const float4*)&Wih[i * 4];
            ushort4 o = {f2bf(v.x), f2bf(v.y), f2bf(v.z), f2bf(v.w)};
            *(ushort4*)&Wih_bf[i * 4] = o;
        }
    } else if (seg == 2) {
        if (i < IN_CH * H) {
            int k = i / H, n = i % H;
            W0t[(size_t)n * IN_CH + k] = f2bf(W0[i]);
        }
    } else {
        if (i < H * H) {
            int k = i / H, n = i % H;
            W1t[(size_t)n * H + k] = f2bf(W1[i]);
        }
    }
}

// ------------------------------------------------------------ MFMA GEMM (wide)
// C[M,Ntot] = A[M,K](bf16) @ Bt[Ntot,K]^T (bf16), fp32 acc, bf16 out.
// 128x256 tile, BK=32, 256 thr = 4 waves (2m x 2n of 64x128).
__global__ __launch_bounds__(256, 2) void gemm_wide(const u16* __restrict__ A,
                                                    const u16* __restrict__ Bt,
                                                    u16* __restrict__ C,
                                                    int M, int K, int Ntot) {
    __shared__ u16 As[128][32];   // 8 KB, NO pad (global_load_lds contiguity)
    __shared__ u16 Bs[256][32];   // 16 KB
    int t = threadIdx.x;
    int m0 = blockIdx.x * 128;
    int n0 = blockIdx.y * 256;
    int wave = t >> 6, lane = t & 63;
    int wm = (wave >> 1) * 64, wn = (wave & 1) * 128;
    int lrow = lane & 15;
    int lq = lane >> 4;

    f32x4 acc[4][8];
#pragma unroll
    for (int i = 0; i < 4; i++)
#pragma unroll
        for (int j = 0; j < 8; j++)
            acc[i][j] = (f32x4){0.f, 0.f, 0.f, 0.f};

    int r0 = t >> 2, q0 = t & 3;
    const u16* gA0 = A + (size_t)(m0 + r0) * K + q0 * 8;
    const u16* gA1 = gA0 + (size_t)64 * K;
    const u16* gB0 = Bt + (size_t)(n0 + r0) * K + q0 * 8;
    const u16* gB1 = gB0 + (size_t)64 * K;
    const u16* gB2 = gB0 + (size_t)128 * K;
    const u16* gB3 = gB0 + (size_t)192 * K;
    u16* lA0 = &As[0][0] + t * 8;
    u16* lA1 = lA0 + 256 * 8;
    u16* lB0 = &Bs[0][0] + t * 8;
    u16* lB1 = lB0 + 256 * 8;
    u16* lB2 = lB0 + 512 * 8;
    u16* lB3 = lB0 + 768 * 8;

    for (int k0 = 0; k0 < K; k0 += 32) {
        __syncthreads();
        async_cp16(gA0 + k0, lA0);
        async_cp16(gA1 + k0, lA1);
        async_cp16(gB0 + k0, lB0);
        async_cp16(gB1 + k0, lB1);
        async_cp16(gB2 + k0, lB2);
        async_cp16(gB3 + k0, lB3);
        __syncthreads();
        short8 af[4], bfr[8];
#pragma unroll
        for (int i = 0; i < 4; i++)
            af[i] = *(const short8*)&As[wm + i * 16 + lrow][lq * 8];
#pragma unroll
        for (int j = 0; j < 8; j++)
            bfr[j] = *(const short8*)&Bs[wn + j * 16 + lrow][lq * 8];
#pragma unroll
        for (int i = 0; i < 4; i++)
#pragma unroll
            for (int j = 0; j < 8; j++)
                acc[i][j] = __builtin_amdgcn_mfma_f32_16x16x32_bf16(af[i], bfr[j], acc[i][j], 0, 0, 0);
    }
    // C/D layout: col = lane&15, row = (lane>>4)*4 + reg
#pragma unroll
    for (int i = 0; i < 4; i++) {
#pragma unroll
        for (int reg = 0; reg < 4; reg++) {
            int gm = m0 + wm + i * 16 + lq * 4 + reg;
            if (gm < M) {
#pragma unroll
                for (int j = 0; j < 8; j++) {
                    int gn = n0 + wn + j * 16 + lrow;
                    C[(size_t)gm * Ntot + gn] = f2bf(acc[i][j][reg]);
                }
            }
        }
    }
}

// ------------------------------------------- attention pre-dots + fp8 encode
__global__ __launch_bounds__(256) void sdot_fp8(const u16* __restrict__ xp,
                                                const float* __restrict__ a_src,
                                                const float* __restrict__ a_dst,
                                                float* __restrict__ s_src,
                                                float* __restrict__ s_dst,
                                                u8* __restrict__ xp8) {
    int wave = threadIdx.x >> 6, lane = threadIdx.x & 63;
    int n = blockIdx.x * 4 + wave;
    int col = lane << 2;
    ushort4 v = *(const ushort4*)&xp[(size_t)n * H + col];
    float4 a1 = *(const float4*)&a_src[col];
    float4 a2 = *(const float4*)&a_dst[col];
    float x0 = bf2f(v.x), x1 = bf2f(v.y), x2 = bf2f(v.z), x3 = bf2f(v.w);
    *(unsigned*)&xp8[(size_t)n * H + col] = fp8_pack4(x0, x1, x2, x3);
    float d1 = x0 * a1.x + x1 * a1.y + x2 * a1.z + x3 * a1.w;
    float d2 = x0 * a2.x + x1 * a2.y + x2 * a2.z + x3 * a2.w;
#pragma unroll
    for (int off = 32; off; off >>= 1) {
        d1 += __shfl_xor(d1, off);
        d2 += __shfl_xor(d2, off);
    }
    if (lane == 0) { s_src[n] = d1; s_dst[n] = d2; }
}

// --------------------------------------------------------- GAT aggregation
// wave per node; CSR stores src directly (eidsSrc); fp8 value gather
__global__ __launch_bounds__(256) void gat_agg_fp8(const u8* __restrict__ xp8,
                                                   const float* __restrict__ s_src,
                                                   const float* __restrict__ s_dst,
                                                   const int* __restrict__ indptr,
                                                   const int* __restrict__ eidsSrc,
                                                   const float* __restrict__ bias,
                                                   u16* __restrict__ out) {
    __shared__ int   sS[4][64];
    __shared__ float sW[4][64];
    int wave = threadIdx.x >> 6, lane = threadIdx.x & 63;
    int n = blockIdx.x * 4 + wave;
    int start = indptr[n];
    int deg = indptr[n + 1] - start;
    float sdn = s_dst[n];
    int col = lane << 2;
    float a0 = 0.f, a1 = 0.f, a2 = 0.f, a3 = 0.f;

    if (deg <= 64) {
        int s = 0;
        float v = -1e30f;
        if (lane < deg) {
            s = eidsSrc[start + lane];
            float u = s_src[s] + sdn;
            v = (u >= 0.f) ? u : NEG_SLOPE * u;
        }
        float m = v;
#pragma unroll
        for (int off = 32; off; off >>= 1) m = fmaxf(m, __shfl_xor(m, off));
        float pw = (lane < deg) ? expf(v - m) : 0.f;
        float dsum = pw;
#pragma unroll
        for (int off = 32; off; off >>= 1) dsum += __shfl_xor(dsum, off);
        sS[wave][lane] = s;
        sW[wave][lane] = pw * (FP8_WSCALE / dsum);
        int j = 0;
        for (; j + 8 <= deg; j += 8) {
            unsigned rv[8];
            float wv[8];
#pragma unroll
            for (int k = 0; k < 8; k++) {
                int sj = sS[wave][j + k];
                wv[k] = sW[wave][j + k];
                rv[k] = *(const unsigned*)&xp8[(size_t)sj * H + col];
            }
#pragma unroll
            for (int k = 0; k < 8; k++) {
                float f0, f1, f2, f3;
                fp8_dec4(rv[k], f0, f1, f2, f3);
                a0 += wv[k] * f0; a1 += wv[k] * f1;
                a2 += wv[k] * f2; a3 += wv[k] * f3;
            }
        }
        for (; j < deg; j++) {
            int sj = sS[wave][j];
            float wj = sW[wave][j];
            unsigned rv = *(const unsigned*)&xp8[(size_t)sj * H + col];
            float f0, f1, f2, f3;
            fp8_dec4(rv, f0, f1, f2, f3);
            a0 += wj * f0; a1 += wj * f1; a2 += wj * f2; a3 += wj * f3;
        }
    } else {
        float m = -1e30f;
        for (int i = lane; i < deg; i += 64) {
            int s = eidsSrc[start + i];
            float u = s_src[s] + sdn;
            u = (u >= 0.f) ? u : NEG_SLOPE * u;
            m = fmaxf(m, u);
        }
#pragma unroll
        for (int off = 32; off; off >>= 1) m = fmaxf(m, __shfl_xor(m, off));
        float dsum = 0.f;
        for (int i = lane; i < deg; i += 64) {
            int s = eidsSrc[start + i];
            float u = s_src[s] + sdn;
            u = (u >= 0.f) ? u : NEG_SLOPE * u;
            dsum += expf(u - m);
        }
#pragma unroll
        for (int off = 32; off; off >>= 1) dsum += __shfl_xor(dsum, off);
        float dinv = FP8_WSCALE / dsum;
        for (int base = 0; base < deg; base += 64) {
            int cnt = min(64, deg - base);
            int s = 0; float w = 0.f;
            if (lane < cnt) {
                s = eidsSrc[start + base + lane];
                float u = s_src[s] + sdn;
                u = (u >= 0.f) ? u : NEG_SLOPE * u;
                w = expf(u - m) * dinv;
            }
            sS[wave][lane] = s;
            sW[wave][lane] = w;
            for (int j = 0; j < cnt; j++) {
                int sj = sS[wave][j];
                float wj = sW[wave][j];
                unsigned rv = *(const unsigned*)&xp8[(size_t)sj * H + col];
                float f0, f1, f2, f3;
                fp8_dec4(rv, f0, f1, f2, f3);
                a0 += wj * f0; a1 += wj * f1; a2 += wj * f2; a3 += wj * f3;
            }
        }
    }
    float4 bv = *(const float4*)&bias[col];
    ushort4 o;
    o.x = f2bf(fmaxf(a0 + bv.x, 0.f));
    o.y = f2bf(fmaxf(a1 + bv.y, 0.f));
    o.z = f2bf(fmaxf(a2 + bv.z, 0.f));
    o.w = f2bf(fmaxf(a3 + bv.w, 0.f));
    *(ushort4*)&out[(size_t)n * H + col] = o;
}

// ------------------------------------------------- GRU gates + pooling (fused)
__global__ __launch_bounds__(256) void gru_gates_pool(const u16* __restrict__ gates,
                                                      const float* __restrict__ b_ih,
                                                      const float* __restrict__ b_hh,
                                                      const int* __restrict__ batch,
                                                      float* __restrict__ pooled,
                                                      int nodeBase, int nodeCount) {
    int t = threadIdx.x;
    int i0 = blockIdx.x * 16;
    if (i0 >= nodeCount) return;
    float bir = b_ih[t], biz = b_ih[256 + t], bin_ = b_ih[512 + t];
    float bhr = b_hh[t], bhz = b_hh[256 + t], bhn = b_hh[512 + t];
    int iend = min(16, nodeCount - i0);
    float acc = 0.f;
    int cur_g = batch[nodeBase + i0];
    for (int i = 0; i < iend; i++) {
        size_t row = (size_t)(i0 + i) * 768;
        float ir = bf2f(gates[row + t]);
        float iz = bf2f(gates[row + 256 + t]);
        float in_ = bf2f(gates[row + 512 + t]);
        float r = 1.f / (1.f + expf(-(ir + bir + bhr)));
        float z = 1.f / (1.f + expf(-(iz + biz + bhz)));
        float nn = tanhf(in_ + bin_ + r * bhn);
        float h = (1.f - z) * nn;
        int g = batch[nodeBase + i0 + i];
        if (g != cur_g) {
            atomicAdd(&pooled[(size_t)cur_g * H + t], acc);
            acc = 0.f;
            cur_g = g;
        }
        acc += h;
    }
    atomicAdd(&pooled[(size_t)cur_g * H + t], acc);
}

// --------------------------------------------------------------- super node
__global__ __launch_bounds__(256) void super_kernel(const float* __restrict__ pooled,
                                                    const float* __restrict__ Wf,
                                                    const float* __restrict__ bf,
                                                    float* __restrict__ sup) {
    __shared__ float smean[256];
    int t = threadIdx.x;
    float s = 0.f;
    for (int g = 0; g < G_GRAPHS; g++) s += pooled[(size_t)g * H + t];
    smean[t] = s / (float)G_GRAPHS;
    __syncthreads();
    float acc = 0.f;
    for (int k = 0; k < H; k++) acc += smean[k] * Wf[(size_t)t * H + k];
    acc += bf[t];
    sup[t] = fmaxf(acc, 0.f);
}

__global__ __launch_bounds__(256) void writeout(const float* __restrict__ pooled,
                                                const float* __restrict__ sup,
                                                float* __restrict__ out) {
    int idx = blockIdx.x * 256 + threadIdx.x;   // G*2H = 65536
    int g = idx >> 9, c = idx & 511;
    out[idx] = (c < H) ? pooled[(size_t)g * H + c] : sup[c - H];
}

// ---------------------------------------------------------------- launcher
extern "C" void kernel_launch(void* const* d_in, const int* in_sizes, int n_in,
                              void* d_out, int out_size, void* d_ws, size_t ws_size,
                              hipStream_t stream) {
    const float* x      = (const float*)d_in[0];
    const int*   ei     = (const int*)d_in[1];
    const int*   batch  = (const int*)d_in[2];
    const float* W0     = (const float*)d_in[3];
    const float* a_src0 = (const float*)d_in[4];
    const float* a_dst0 = (const float*)d_in[5];
    const float* b0     = (const float*)d_in[6];
    const float* W1     = (const float*)d_in[7];
    const float* a_src1 = (const float*)d_in[8];
    const float* a_dst1 = (const float*)d_in[9];
    const float* b1     = (const float*)d_in[10];
    const float* W_ih   = (const float*)d_in[11];
    const float* b_ih   = (const float*)d_in[13];
    const float* b_hh   = (const float*)d_in[14];
    const float* Wf     = (const float*)d_in[15];
    const float* bf     = (const float*)d_in[16];
    float* out = (float*)d_out;

    char* p = (char*)d_ws;
    auto alloc = [&](size_t bytes) -> void* {
        void* r = (void*)p;
        p += (bytes + 255) & ~(size_t)255;
        return r;
    };
    u16*   xp_bf  = (u16*)alloc((size_t)N_PAD * H * 2);
    u16*   h_bf   = (u16*)alloc((size_t)N_PAD * H * 2);
    u16*   x_bf   = (u16*)alloc((size_t)N_PAD * IN_CH * 2);   // dead after gemm L0
    u8*    xp8    = (u8*)x_bf;                                // alias: N_PAD*H*1
    u16*   gatesC = (u16*)alloc((size_t)GRU_CHUNK * 3 * H * 2);
    u16*   W0t    = (u16*)alloc((size_t)H * IN_CH * 2);
    u16*   W1t    = (u16*)alloc((size_t)H * H * 2);
    u16*   Wih_bf = (u16*)alloc((size_t)3 * H * H * 2);
    float* s_src  = (float*)alloc((size_t)N_NODES * 4);
    float* s_dst  = (float*)alloc((size_t)N_NODES * 4);
    int2*  rec    = (int2*)alloc((size_t)N_EDGES * 8);
    int*   eidsSrc= (int*)alloc((size_t)ET * 4);
    int*   counts = (int*)alloc((size_t)N_NODES * 4);
    int*   incl   = (int*)alloc((size_t)N_NODES * 4);
    int*   indptr = (int*)alloc((size_t)(N_NODES + 1) * 4);
    int*   gBkt   = (int*)alloc((size_t)(NB + 1) * 4);
    int*   bktOff = (int*)alloc((size_t)(NB + 1) * 4);
    int*   bktCur = (int*)alloc((size_t)(NB + 1) * 4);
    int*   bSums  = (int*)alloc(256 * 4);
    int*   bOff   = (int*)alloc(256 * 4);
    float* pooled = (float*)alloc((size_t)G_GRAPHS * H * 4);
    float* sup    = (float*)alloc((size_t)H * 4);

    const int SB = (N_NODES + 255) / 256;            // 196
    // ---- CSR build (bucketed counting sort) ----
    hipMemsetAsync(gBkt, 0, (size_t)NB * 4, stream);
    bucket_hist<<<NB, 256, 0, stream>>>(ei, gBkt);
    bucket_scan<<<1, 512, 0, stream>>>(gBkt, bktOff, bktCur);
    bucket_scatter<<<(N_EDGES + 256 * EPT - 1) / (256 * EPT), 256, 0, stream>>>(ei, bktCur, rec);
    node_hist<<<NB, 256, 0, stream>>>(rec, bktOff, counts);
    scan_block<<<SB, 256, 0, stream>>>(counts, incl, bSums);
    scan_sums<<<1, 256, 0, stream>>>(bSums, bOff, SB);
    scan_finalize<<<SB, 256, 0, stream>>>(incl, bOff, indptr);
    final_scatter<<<NB, 256, 0, stream>>>(rec, bktOff, indptr, eidsSrc);

    // conversions
    prep_kernel<<<dim3((N_NODES * IN_CH / 4 + 255) / 256, 4), 256, 0, stream>>>(
        x, W_ih, W0, W1, x_bf, Wih_bf, W0t, W1t);

    const int MB = (N_NODES + 127) / 128;            // 391
    const int WB = N_NODES / 4;                      // 12500
    // GAT layer 0
    gemm_wide<<<dim3(MB, 1), 256, 0, stream>>>(x_bf, W0t, xp_bf, N_NODES, IN_CH, H);
    sdot_fp8<<<WB, 256, 0, stream>>>(xp_bf, a_src0, a_dst0, s_src, s_dst, xp8);
    gat_agg_fp8<<<WB, 256, 0, stream>>>(xp8, s_src, s_dst, indptr, eidsSrc, b0, h_bf);
    // GAT layer 1
    gemm_wide<<<dim3(MB, 1), 256, 0, stream>>>(h_bf, W1t, xp_bf, N_NODES, H, H);
    sdot_fp8<<<WB, 256, 0, stream>>>(xp_bf, a_src1, a_dst1, s_src, s_dst, xp8);
    gat_agg_fp8<<<WB, 256, 0, stream>>>(xp8, s_src, s_dst, indptr, eidsSrc, b1, h_bf);
    // GRU (chunked) + fused pooling
    hipMemsetAsync(pooled, 0, (size_t)G_GRAPHS * H * 4, stream);
    for (int base = 0; base < N_NODES; base += GRU_CHUNK) {
        int cnt = min(GRU_CHUNK, N_NODES - base);
        gemm_wide<<<dim3((cnt + 127) / 128, 3), 256, 0, stream>>>(
            h_bf + (size_t)base * H, Wih_bf, gatesC, cnt, H, 3 * H);
        gru_gates_pool<<<(cnt + 15) / 16, 256, 0, stream>>>(gatesC, b_ih, b_hh, batch, pooled, base, cnt);
    }
    // super node + writeout
    super_kernel<<<1, 256, 0, stream>>>(pooled, Wf, bf, sup);
    writeout<<<(G_GRAPHS * 2 * H) / 256, 256, 0, stream>>>(pooled, sup, out);
}